// Round 1
// 1030.632 us; speedup vs baseline: 1.0278x; 1.0278x over previous
//
#include <hip/hip_runtime.h>
#include <math.h>

// Problem constants
#define HH 128
#define WW 128
#define CC 128
#define KK 9
#define NPIX 16384           // H*W
#define NELEM 2097152        // NPIX*C
#define EPS 1e-5f

// Workspace layout (float offsets)
#define OFF_WCOMB 0          // [2][9][27][128] fp32      = 62208
#define OFF_BCOMB 62208      // [2][32] fp32              = 64
#define OFF_WB    62272      // fp16 B-frag deform w: 2*147456 ushort = 147456 floats
#define OFF_WC    209728     // fp16 B-frag conv w:   2*36864 ushort  = 36864 floats
#define OFF_APROJ 246592     // hi/lo bf16 A-frag proj w: 389120 ushort = 194560 floats
#define OFF_OFFM  441152     // [16384][27]               = 442368
#define OFF_BUFA  883520     // [16384][128]              = 2097152
#define OFF_BUFB  2980672    // [16384][128]              = 2097152
#define OFF_STATS 5077824    // [10][2][128]              = 2560
#define WS_FLOATS 5080384    // ~20.3 MB

typedef __bf16    bf16x8 __attribute__((ext_vector_type(8)));
typedef _Float16  f16x8  __attribute__((ext_vector_type(8)));
typedef float     floatx4 __attribute__((ext_vector_type(4)));

__device__ __forceinline__ unsigned short f2bf(float f) {
    unsigned u = __float_as_uint(f);
    return (unsigned short)((u + 0x7FFF + ((u >> 16) & 1)) >> 16);   // RNE
}
__device__ __forceinline__ float bf2f(unsigned short h) {
    return __uint_as_float(((unsigned)h) << 16);
}
__device__ __forceinline__ unsigned short f2h(float f) {
    _Float16 h = (_Float16)f;                                        // v_cvt_f16_f32 (RNE)
    return __builtin_bit_cast(unsigned short, h);
}

// ---------------------------------------------------------------------------
// Setup: compose [ow;mw] @ cw -> 27-ch conv weights (layout [k][o][c]),
// composed bias, and swizzle cw into fp16 MFMA B-fragment order (deform):
//   kc = s*32 + (lane>>4)*8 + j (kc = k*128+c), o = t*16 + (lane&15)
// ---------------------------------------------------------------------------
__global__ __launch_bounds__(256) void setup_conv(
    const float* __restrict__ cw, const float* __restrict__ cb,
    const float* __restrict__ ow, const float* __restrict__ mw,
    float* __restrict__ wcomb, float* __restrict__ bcomb,
    unsigned short* __restrict__ wBu)
{
    int tid = blockIdx.x * 256 + threadIdx.x;
    if (tid < 31104) {
        int c = tid & 127;
        int o = (tid >> 7) % 27;
        int k = tid / 3456;                  // k in [0,9)
        const float* sel = (o < 18) ? (ow + o * 128) : (mw + (o - 18) * 128);
        float v = 0.f;
        for (int cp = 0; cp < 128; ++cp)
            v = fmaf(sel[cp], cw[cp * 1152 + c * 9 + k], v);
        wcomb[tid] = v;                      // wcomb[k][o][c]
    } else if (tid < 31104 + 27) {
        int o = tid - 31104;
        const float* sel = (o < 18) ? (ow + o * 128) : (mw + (o - 18) * 128);
        float v = 0.f;
        for (int cp = 0; cp < 128; ++cp)
            v = fmaf(sel[cp], cb[cp], v);
        bcomb[o] = v;
    } else if (tid >= 32768 && tid < 32768 + 147456) {
        int i = tid - 32768;
        int j    = i & 7;
        int lane = (i >> 3) & 63;
        int t    = (i >> 9) & 7;
        int s    = i >> 12;                  // 0..35
        int kc   = s * 32 + ((lane >> 4) << 3) + j;
        int o    = t * 16 + (lane & 15);
        wBu[i] = f2h(cw[o * 1152 + (kc & 127) * 9 + (kc >> 7)]);
    }
}

// ---------------------------------------------------------------------------
// Swizzle composed conv weights wcomb[k][o][c] into fp16 B-frag order for the
// conv_offm MFMA (27 outputs padded to 32 -> 2 out-tiles):
//   i = ((s*2 + t)*64 + lane)*8 + j; kc = s*32 + (lane>>4)*8 + j;
//   o = t*16 + (lane&15). 36864 elements per conv block.
// ---------------------------------------------------------------------------
__global__ __launch_bounds__(256) void setup_convfrag(
    const float* __restrict__ wcomb, unsigned short* __restrict__ wC)
{
    int i = blockIdx.x * 256 + threadIdx.x;
    if (i >= 36864) return;
    int j    = i & 7;
    int lane = (i >> 3) & 63;
    int grp  = i >> 9;                       // s*2 + t
    int t = grp & 1, s = grp >> 1;
    int kc = s * 32 + ((lane >> 4) << 3) + j;
    int o  = t * 16 + (lane & 15);
    int c = kc & 127, k = kc >> 7;
    float v = (o < 27) ? wcomb[k * 3456 + o * 128 + c] : 0.f;
    wC[i] = f2h(v);
}

// ---------------------------------------------------------------------------
// Swizzle 8 projection matrices [O][128] into hi/lo bf16 A-fragment planes.
// ---------------------------------------------------------------------------
__global__ __launch_bounds__(256) void setup_projA(
    const float* __restrict__ s0, const float* __restrict__ s1,
    const float* __restrict__ s2, const float* __restrict__ s3,
    const float* __restrict__ s4, const float* __restrict__ s5,
    const float* __restrict__ s6, const float* __restrict__ s7,
    unsigned short* __restrict__ dst)
{
    const int Os[8]   = {20, 80, 150, 150, 210, 210, 308, 308};
    const int nOt[8]  = {2, 5, 10, 10, 14, 14, 20, 20};
    const int tOff[8] = {0, 4096, 14336, 34816, 55296, 83968, 112640, 153600};
    const int dOff[8] = {0, 8192, 28672, 69632, 110592, 167936, 225280, 307200};
    int tid = blockIdx.x * 256 + threadIdx.x;
    if (tid >= 194560) return;
    int m = 0;
    #pragma unroll
    for (int q = 1; q < 8; ++q) if (tid >= tOff[q]) m = q;
    const float* src;
    switch (m) {
        case 0: src = s0; break; case 1: src = s1; break;
        case 2: src = s2; break; case 3: src = s3; break;
        case 4: src = s4; break; case 5: src = s5; break;
        case 6: src = s6; break; default: src = s7; break;
    }
    int i = tid - tOff[m];
    int j    = i & 7;
    int lane = (i >> 3) & 63;
    int s    = (i >> 9) & 3;
    int ot   = i >> 11;
    int o = ot * 16 + (lane & 15);
    int c = s * 32 + ((lane >> 4) << 3) + j;
    float v = (o < Os[m]) ? src[o * 128 + c] : 0.f;
    unsigned short h = f2bf(v);
    unsigned short l = f2bf(v - bf2f(h));
    const int hiSize = nOt[m] * 2048;
    dst[dOff[m] + i] = h;
    dst[dOff[m] + hiSize + i] = l;
}

// ---------------------------------------------------------------------------
// conv_offm via fp16 MFMA. 16 px/block, 4 waves = (out-tile t, K-half kh).
// Gather: 9-tap clipped neighborhood -> fp16 LDS rows (deform layout,
// stride 1160 halves). Branchless (clamp + select-0) so the unrolled tap
// loop pipelines all 9 loads. 18 MFMAs/wave; cross-wave K-reduction through
// recycled LDS; 16-lane epilogue does softmax + offset assembly.
// ---------------------------------------------------------------------------
__global__ __launch_bounds__(256, 4) void conv_offm(
    const float* __restrict__ x, const unsigned short* __restrict__ wC,
    const float* __restrict__ bcomb, float* __restrict__ offm)
{
    __shared__ unsigned short smp[16 * 1160];   // 37120 B -> 4 blocks/CU
    float* red  = (float*)smp;                  // recycled: [2][16][16] = 512 f
    float* vals = red + 512;                    // recycled: [16][33]    = 528 f

    const int lane = threadIdx.x & 63;
    const int wid  = threadIdx.x >> 6;
    const int gp0  = blockIdx.x * 16;
    const float2* xl = (const float2*)x + lane; // lane = channel pair

    // ---- gather: wave wid handles pixels 4*wid..4*wid+3; lane = chan pair --
    for (int pp = 0; pp < 4; ++pp) {
        const int pl = wid * 4 + pp;
        const int gp = gp0 + pl;
        const int h0 = gp >> 7, w0 = gp & 127;
        unsigned* dst = (unsigned*)smp + pl * 580 + lane;
        #pragma unroll
        for (int k = 0; k < 9; ++k) {
            const int ny = h0 + k / 3 - 1;
            const int nx = w0 + k % 3 - 1;
            const int cy = min(max(ny, 0), 127);
            const int cx = min(max(nx, 0), 127);
            const float2 v = xl[((cy << 7) + cx) << 6];
            const unsigned pack = (unsigned)f2h(v.x) | ((unsigned)f2h(v.y) << 16);
            const bool ok = ((unsigned)ny < 128u) && ((unsigned)nx < 128u);
            dst[k * 64] = ok ? pack : 0u;
        }
    }
    __syncthreads();

    // ---- MFMA: wave = (t = wid&1, kh = wid>>1), 18 K-steps each ----
    const int t    = wid & 1;
    const int kh   = wid >> 1;
    const int mrow = lane & 15;
    const int quad = lane >> 4;
    floatx4 acc = {0.f, 0.f, 0.f, 0.f};
    const unsigned short* arow = smp + mrow * 1160 + quad * 8;
    #pragma unroll
    for (int j = 0; j < 18; ++j) {
        const int s = kh * 18 + j;
        const f16x8 a = *(const f16x8*)(arow + s * 32);
        const f16x8 b = *(const f16x8*)(wC + (((s * 2 + t) * 64 + lane) << 3));
        acc = __builtin_amdgcn_mfma_f32_16x16x32_f16(a, b, acc, 0, 0, 0);
    }
    __syncthreads();   // all smp reads done; safe to recycle as red/vals

    // D: row (pixel) = quad*4+r, col (channel n) = lane&15
    if (kh == 1) {
        #pragma unroll
        for (int r = 0; r < 4; ++r)
            red[t * 256 + (quad * 4 + r) * 16 + mrow] = acc[r];
    }
    __syncthreads();
    if (kh == 0) {
        #pragma unroll
        for (int r = 0; r < 4; ++r) {
            const float sv = acc[r] + red[t * 256 + (quad * 4 + r) * 16 + mrow];
            vals[(quad * 4 + r) * 33 + t * 16 + mrow] = sv;
        }
    }
    __syncthreads();

    // ---- epilogue: lane p < 16 handles pixel p ----
    if (threadIdx.x < 16) {
        const int p  = threadIdx.x;
        const int gp = gp0 + p;
        const int hh = gp >> 7, ww = gp & 127;
        float v[27];
        #pragma unroll
        for (int o = 0; o < 27; ++o) v[o] = vals[p * 33 + o] + bcomb[o];
        float mx = v[18];
        #pragma unroll
        for (int k = 1; k < 9; ++k) mx = fmaxf(mx, v[18 + k]);
        float e[9], se = 0.f;
        #pragma unroll
        for (int k = 0; k < 9; ++k) { e[k] = expf(v[18 + k] - mx); se += e[k]; }
        const float inv = 1.f / se;
        float* ob = offm + gp * 27;
        #pragma unroll
        for (int k = 0; k < 9; ++k) {
            ob[k]      = (float)(hh - 1 + k / 3) + v[2 * k];      // py
            ob[9 + k]  = (float)(ww - 1 + k % 3) + v[2 * k + 1];  // px
            ob[18 + k] = e[k] * inv;                              // mask
        }
    }
}

// ---------------------------------------------------------------------------
// deform: bilinear gather -> fp16 LDS, then MFMA 16x16x32 f16 GEMM.
// 16 px/block, 4 waves. LDS rows padded to 1160 halves.
// Gather is branchless: corner coords are clamped, validity+mask folded
// into the 4 bilinear weights, and the tap loop fully unrolled so all 36
// L2 loads per pixel pipeline (this kernel was latency-bound: VALUBusy 24%,
// MfmaUtil 3.5%, HBM 3.9% — pure dependency stalls).
// Epilogue also accumulates per-channel sum/sumsq (replaces stats_kernel).
// ---------------------------------------------------------------------------
__global__ __launch_bounds__(256, 4) void deform_kernel(
    const float* __restrict__ x, const float* __restrict__ offm,
    const unsigned short* __restrict__ wBu, const float* __restrict__ cb,
    float* __restrict__ y, float* __restrict__ st)
{
    __shared__ unsigned short smp[16 * 1160];   // 37120 B -> 4 blocks/CU

    const int lane = threadIdx.x & 63;
    const int wid  = threadIdx.x >> 6;          // 0..3
    const int gp0  = blockIdx.x * 16;
    const float2* xl = (const float2*)x + lane; // lane = channel pair

    // ---- phase 1: wave wid gathers pixels [4*wid, 4*wid+4) ----
    for (int pp = 0; pp < 4; ++pp) {
        const int pl = wid * 4 + pp;            // 0..15
        const float* ob = offm + (gp0 + pl) * 27;
        float pv[27];
        #pragma unroll
        for (int o = 0; o < 27; ++o) pv[o] = ob[o];
        unsigned* dst = (unsigned*)smp + pl * 580 + lane;
        #pragma unroll
        for (int k = 0; k < 9; ++k) {
            const float py = pv[k], px = pv[9 + k], mk = pv[18 + k];
            const float y0f = floorf(py), x0f = floorf(px);
            const int iy0 = (int)y0f, ix0 = (int)x0f;
            const float wy1 = py - y0f, wy0 = 1.f - wy1;
            const float wx1 = px - x0f, wx0 = 1.f - wx1;
            const int cy0 = min(max(iy0, 0), 127);
            const int cy1 = min(max(iy0 + 1, 0), 127);
            const int cx0 = min(max(ix0, 0), 127);
            const int cx1 = min(max(ix0 + 1, 0), 127);
            const float vy0 = ((unsigned)iy0       < 128u) ? 1.f : 0.f;
            const float vy1 = ((unsigned)(iy0 + 1) < 128u) ? 1.f : 0.f;
            const float vx0 = ((unsigned)ix0       < 128u) ? 1.f : 0.f;
            const float vx1 = ((unsigned)(ix0 + 1) < 128u) ? 1.f : 0.f;
            const float w00 = wy0 * wx0 * vy0 * vx0 * mk;
            const float w01 = wy0 * wx1 * vy0 * vx1 * mk;
            const float w10 = wy1 * wx0 * vy1 * vx0 * mk;
            const float w11 = wy1 * wx1 * vy1 * vx1 * mk;
            const float2 g00 = xl[((cy0 << 7) + cx0) << 6];
            const float2 g01 = xl[((cy0 << 7) + cx1) << 6];
            const float2 g10 = xl[((cy1 << 7) + cx0) << 6];
            const float2 g11 = xl[((cy1 << 7) + cx1) << 6];
            const float s0 = fmaf(w00, g00.x, fmaf(w01, g01.x,
                             fmaf(w10, g10.x, w11 * g11.x)));
            const float s1 = fmaf(w00, g00.y, fmaf(w01, g01.y,
                             fmaf(w10, g10.y, w11 * g11.y)));
            dst[k * 64] = (unsigned)f2h(s0) | ((unsigned)f2h(s1) << 16);
        }
    }
    __syncthreads();

    // ---- phase 2: MFMA. wave wid handles out-tiles t = 2*wid, 2*wid+1 ----
    floatx4 acc0 = {0.f, 0.f, 0.f, 0.f};
    floatx4 acc1 = {0.f, 0.f, 0.f, 0.f};
    const int mrow = lane & 15;
    const int quad = lane >> 4;
    const unsigned short* arow = smp + mrow * 1160 + quad * 8;
    const int t0 = wid * 2, t1 = wid * 2 + 1;
    #pragma unroll 4
    for (int s = 0; s < 36; ++s) {
        const f16x8 a  = *(const f16x8*)(arow + s * 32);
        const f16x8 b0 = *(const f16x8*)(wBu + (((s * 8 + t0) * 64 + lane) << 3));
        const f16x8 b1 = *(const f16x8*)(wBu + (((s * 8 + t1) * 64 + lane) << 3));
        acc0 = __builtin_amdgcn_mfma_f32_16x16x32_f16(a, b0, acc0, 0, 0, 0);
        acc1 = __builtin_amdgcn_mfma_f32_16x16x32_f16(a, b1, acc1, 0, 0, 0);
    }

    // ---- epilogue: D col=lane&15, row=quad*4+reg; add conv bias;
    //      accumulate per-channel sum/sumsq for the BN normalization ----
    const int n0 = t0 * 16 + mrow, n1 = t1 * 16 + mrow;
    const float bias0 = cb[n0], bias1 = cb[n1];
    float s0 = 0.f, q0 = 0.f, s1 = 0.f, q1 = 0.f;
    #pragma unroll
    for (int r = 0; r < 4; ++r) {
        float* yr = y + (size_t)(gp0 + quad * 4 + r) * 128;
        const float v0 = acc0[r] + bias0;
        const float v1 = acc1[r] + bias1;
        yr[n0] = v0;
        yr[n1] = v1;
        s0 += v0; q0 = fmaf(v0, v0, q0);
        s1 += v1; q1 = fmaf(v1, v1, q1);
    }
    // each channel is owned by exactly one wave; reduce over the 4 quads
    s0 += __shfl_xor(s0, 16); q0 += __shfl_xor(q0, 16);
    s1 += __shfl_xor(s1, 16); q1 += __shfl_xor(q1, 16);
    s0 += __shfl_xor(s0, 32); q0 += __shfl_xor(q0, 32);
    s1 += __shfl_xor(s1, 32); q1 += __shfl_xor(q1, 32);
    if (quad == 0) {
        atomicAdd(&st[n0], s0);
        atomicAdd(&st[n1], s1);
        atomicAdd(&st[128 + n0], q0);
        atomicAdd(&st[128 + n1], q1);
    }
}

__global__ __launch_bounds__(256) void norm_relu(
    float* __restrict__ y, const float* __restrict__ stats,
    const float* __restrict__ bg, const float* __restrict__ bb)
{
    const int g = blockIdx.x * 256 + threadIdx.x;
    const int c = g & 127;
    const float mean = stats[c] * (1.f / 16384.f);
    const float var  = stats[128 + c] * (1.f / 16384.f) - mean * mean;
    const float rstd = rsqrtf(var + EPS);
    const float scale = bg[c] * rstd;
    const float shift = bb[c] - mean * scale;
    for (int i = g; i < NELEM; i += 65536)
        y[i] = fmaxf(fmaf(y[i], scale, shift), 0.f);
}

// ---------------------------------------------------------------------------
// 1x1 projection as hi/lo-split bf16 MFMA GEMM (fp32-accurate).
// ---------------------------------------------------------------------------
__global__ __launch_bounds__(256) void proj_kernel(
    const float* __restrict__ xin, const unsigned short* __restrict__ aP,
    float* __restrict__ out, int O, int hiSize, int accum)
{
    __shared__ unsigned short sh[64 * 136];
    __shared__ unsigned short sl[64 * 136];
    const int gp0 = blockIdx.x * 64;

    // stage 64 px x 128 c, split into hi/lo bf16 (dword-packed writes)
    for (int i = threadIdx.x; i < 4096; i += 256) {
        const int p = i >> 6, c2 = (i & 63) * 2;
        const float2 v = *(const float2*)(xin + (gp0 + p) * 128 + c2);
        const unsigned short h0 = f2bf(v.x), h1 = f2bf(v.y);
        const unsigned short l0 = f2bf(v.x - bf2f(h0)), l1 = f2bf(v.y - bf2f(h1));
        ((unsigned*)sh)[p * 68 + (c2 >> 1)] = (unsigned)h0 | ((unsigned)h1 << 16);
        ((unsigned*)sl)[p * 68 + (c2 >> 1)] = (unsigned)l0 | ((unsigned)l1 << 16);
    }
    __syncthreads();

    const int lane = threadIdx.x & 63;
    const int wid  = threadIdx.x >> 6;
    const int quad = lane >> 4;
    const int nrow = lane & 15;
    const int nOt  = (O + 15) >> 4;

    for (int ot = wid; ot < nOt; ot += 4) {
        bf16x8 Ah[4], Al[4];
        #pragma unroll
        for (int s = 0; s < 4; ++s) {
            const int idx = ((ot * 4 + s) * 64 + lane) * 8;
            Ah[s] = *(const bf16x8*)(aP + idx);
            Al[s] = *(const bf16x8*)(aP + hiSize + idx);
        }
        #pragma unroll
        for (int pt = 0; pt < 4; ++pt) {
            floatx4 acc = {0.f, 0.f, 0.f, 0.f};
            const int roff = (pt * 16 + nrow) * 136 + quad * 8;
            #pragma unroll
            for (int s = 0; s < 4; ++s) {
                const bf16x8 Bh = *(const bf16x8*)(sh + roff + s * 32);
                const bf16x8 Bl = *(const bf16x8*)(sl + roff + s * 32);
                acc = __builtin_amdgcn_mfma_f32_16x16x32_bf16(Ah[s], Bh, acc, 0, 0, 0);
                acc = __builtin_amdgcn_mfma_f32_16x16x32_bf16(Al[s], Bh, acc, 0, 0, 0);
                acc = __builtin_amdgcn_mfma_f32_16x16x32_bf16(Ah[s], Bl, acc, 0, 0, 0);
            }
            #pragma unroll
            for (int r = 0; r < 4; ++r) {
                const int o = ot * 16 + quad * 4 + r;
                if (o < O) {
                    float* dst = out + (size_t)o * NPIX + gp0 + pt * 16 + nrow;
                    *dst = accum ? (*dst + acc[r]) : acc[r];
                }
            }
        }
    }
}

// ---------------------------------------------------------------------------
// Final layernorm over the W axis: one wave per (c,h) row of 128.
// ---------------------------------------------------------------------------
__global__ __launch_bounds__(256) void final_ln(
    float* __restrict__ out, const float* __restrict__ lnw,
    const float* __restrict__ lnb)
{
    const int lane = threadIdx.x & 63;
    const int wid  = threadIdx.x >> 6;
    const int row  = blockIdx.x * 4 + wid;          // 98304 rows
    float* rp = out + row * 128;
    const float v0 = rp[lane], v1 = rp[lane + 64];
    float s = v0 + v1;
    float q = v0 * v0 + v1 * v1;
    #pragma unroll
    for (int m = 32; m; m >>= 1) {
        s += __shfl_xor(s, m);
        q += __shfl_xor(q, m);
    }
    const float mean = s * (1.f / 128.f);
    const float var  = q * (1.f / 128.f) - mean * mean;
    const float rstd = rsqrtf(var + EPS);
    rp[lane]      = (v0 - mean) * rstd * lnw[lane]      + lnb[lane];
    rp[lane + 64] = (v1 - mean) * rstd * lnw[lane + 64] + lnb[lane + 64];
}

// ---------------------------------------------------------------------------
extern "C" void kernel_launch(void* const* d_in, const int* in_sizes, int n_in,
                              void* d_out, int out_size, void* d_ws, size_t ws_size,
                              hipStream_t stream)
{
    const float* xin[5];
    for (int i = 0; i < 5; ++i) xin[i] = (const float*)d_in[i];
    const float* b_cw[2] = {(const float*)d_in[5],  (const float*)d_in[11]};
    const float* b_cb[2] = {(const float*)d_in[6],  (const float*)d_in[12]};
    const float* b_ow[2] = {(const float*)d_in[7],  (const float*)d_in[13]};
    const float* b_mw[2] = {(const float*)d_in[8],  (const float*)d_in[14]};
    const float* b_bg[2] = {(const float*)d_in[9],  (const float*)d_in[15]};
    const float* b_bb[2] = {(const float*)d_in[10], (const float*)d_in[16]};
    const float* pw[8];
    for (int i = 0; i < 8; ++i) pw[i] = (const float*)d_in[17 + i];
    const float* lnw = (const float*)d_in[25];
    const float* lnb = (const float*)d_in[26];

    float* W = (float*)d_ws;
    float* out = (float*)d_out;
    unsigned short* wB = (unsigned short*)(W + OFF_WB);
    unsigned short* wC = (unsigned short*)(W + OFF_WC);
    unsigned short* aP = (unsigned short*)(W + OFF_APROJ);

    hipMemsetAsync(W + OFF_STATS, 0, 2560 * sizeof(float), stream);

    setup_conv<<<704, 256, 0, stream>>>(b_cw[0], b_cb[0], b_ow[0], b_mw[0],
        W + OFF_WCOMB, W + OFF_BCOMB, wB);
    setup_conv<<<704, 256, 0, stream>>>(b_cw[1], b_cb[1], b_ow[1], b_mw[1],
        W + OFF_WCOMB + 31104, W + OFF_BCOMB + 32, wB + 147456);
    setup_convfrag<<<144, 256, 0, stream>>>(W + OFF_WCOMB, wC);
    setup_convfrag<<<144, 256, 0, stream>>>(W + OFF_WCOMB + 31104, wC + 36864);
    setup_projA<<<760, 256, 0, stream>>>(pw[0], pw[1], pw[2], pw[3],
        pw[4], pw[5], pw[6], pw[7], aP);

    static const int Obase[5] = {0, 20, 100, 250, 460};
    static const int Ocnt[5]  = {20, 80, 150, 210, 308};
    // A-frag plane offsets (ushort) and hi-plane sizes
    static const int aOffA[5] = {0, 8192, 28672, 110592, 225280};      // c1,c2,c3a,c4a,c5a
    static const int aOffB[5] = {0, 0, 69632, 167936, 307200};         // c3b,c4b,c5b
    static const int hiSz[5]  = {4096, 10240, 20480, 28672, 40960};

    for (int img = 0; img < 5; ++img) {
        for (int blk = 0; blk < 2; ++blk) {
            const float* xb = (blk == 0) ? xin[img] : (W + OFF_BUFA);
            float* yb = (blk == 0) ? (W + OFF_BUFA) : (W + OFF_BUFB);
            float* st = W + OFF_STATS + (img * 2 + blk) * 256;
            conv_offm<<<1024, 256, 0, stream>>>(
                xb, wC + blk * 36864, W + OFF_BCOMB + blk * 32, W + OFF_OFFM);
            deform_kernel<<<1024, 256, 0, stream>>>(
                xb, W + OFF_OFFM, wB + blk * 147456, b_cb[blk], yb, st);
            norm_relu<<<256, 256, 0, stream>>>(yb, st, b_bg[blk], b_bb[blk]);
        }
        float* outb = out + (size_t)Obase[img] * NPIX;
        proj_kernel<<<256, 256, 0, stream>>>(
            W + OFF_BUFB, aP + aOffA[img], outb, Ocnt[img], hiSz[img], 0);
        if (img >= 2)
            proj_kernel<<<256, 256, 0, stream>>>(
                xin[img], aP + aOffB[img], outb, Ocnt[img], hiSz[img], 1);
    }
    final_ln<<<24576, 256, 0, stream>>>(out, lnw, lnb);
}

// Round 2
// 804.411 us; speedup vs baseline: 1.3168x; 1.2812x over previous
//
#include <hip/hip_runtime.h>
#include <math.h>

// Problem constants
#define HH 128
#define WW 128
#define CC 128
#define KK 9
#define NPIX 16384           // H*W
#define NELEM 2097152        // NPIX*C
#define EPS 1e-5f

// Workspace layout (float offsets)
#define OFF_WCOMB 0          // [2][9][27][128] fp32      = 62208
#define OFF_BCOMB 62208      // [2][32] fp32              = 64
#define OFF_WB    62272      // fp16 B-frag deform w: 2*147456 ushort = 147456 floats
#define OFF_WC    209728     // fp16 B-frag conv w:   2*36864 ushort  = 36864 floats
#define OFF_APROJ 246592     // hi/lo bf16 A-frag proj w: 389120 ushort = 194560 floats
#define OFF_OFFM  441152     // [16384][27]               = 442368
#define OFF_BUFA  883520     // [16384][128]              = 2097152
#define OFF_BUFB  2980672    // [16384][128]              = 2097152
#define OFF_STATS 5077824    // [10][2][128]              = 2560
#define WS_FLOATS 5080384    // ~20.3 MB

typedef __bf16    bf16x8 __attribute__((ext_vector_type(8)));
typedef _Float16  f16x8  __attribute__((ext_vector_type(8)));
typedef float     floatx4 __attribute__((ext_vector_type(4)));

__device__ __forceinline__ unsigned short f2bf(float f) {
    unsigned u = __float_as_uint(f);
    return (unsigned short)((u + 0x7FFF + ((u >> 16) & 1)) >> 16);   // RNE
}
__device__ __forceinline__ float bf2f(unsigned short h) {
    return __uint_as_float(((unsigned)h) << 16);
}
__device__ __forceinline__ unsigned short f2h(float f) {
    _Float16 h = (_Float16)f;                                        // v_cvt_f16_f32 (RNE)
    return __builtin_bit_cast(unsigned short, h);
}

// ---------------------------------------------------------------------------
// Setup: compose [ow;mw] @ cw -> 27-ch conv weights (layout [k][o][c]),
// composed bias, and swizzle cw into fp16 MFMA B-fragment order (deform):
//   kc = s*32 + (lane>>4)*8 + j (kc = k*128+c), o = t*16 + (lane&15)
// ---------------------------------------------------------------------------
__global__ __launch_bounds__(256) void setup_conv(
    const float* __restrict__ cw, const float* __restrict__ cb,
    const float* __restrict__ ow, const float* __restrict__ mw,
    float* __restrict__ wcomb, float* __restrict__ bcomb,
    unsigned short* __restrict__ wBu)
{
    int tid = blockIdx.x * 256 + threadIdx.x;
    if (tid < 31104) {
        int c = tid & 127;
        int o = (tid >> 7) % 27;
        int k = tid / 3456;                  // k in [0,9)
        const float* sel = (o < 18) ? (ow + o * 128) : (mw + (o - 18) * 128);
        float v = 0.f;
        for (int cp = 0; cp < 128; ++cp)
            v = fmaf(sel[cp], cw[cp * 1152 + c * 9 + k], v);
        wcomb[tid] = v;                      // wcomb[k][o][c]
    } else if (tid < 31104 + 27) {
        int o = tid - 31104;
        const float* sel = (o < 18) ? (ow + o * 128) : (mw + (o - 18) * 128);
        float v = 0.f;
        for (int cp = 0; cp < 128; ++cp)
            v = fmaf(sel[cp], cb[cp], v);
        bcomb[o] = v;
    } else if (tid >= 32768 && tid < 32768 + 147456) {
        int i = tid - 32768;
        int j    = i & 7;
        int lane = (i >> 3) & 63;
        int t    = (i >> 9) & 7;
        int s    = i >> 12;                  // 0..35
        int kc   = s * 32 + ((lane >> 4) << 3) + j;
        int o    = t * 16 + (lane & 15);
        wBu[i] = f2h(cw[o * 1152 + (kc & 127) * 9 + (kc >> 7)]);
    }
}

// ---------------------------------------------------------------------------
// Swizzle composed conv weights wcomb[k][o][c] into fp16 B-frag order for the
// conv_offm MFMA (27 outputs padded to 32 -> 2 out-tiles).
// ---------------------------------------------------------------------------
__global__ __launch_bounds__(256) void setup_convfrag(
    const float* __restrict__ wcomb, unsigned short* __restrict__ wC)
{
    int i = blockIdx.x * 256 + threadIdx.x;
    if (i >= 36864) return;
    int j    = i & 7;
    int lane = (i >> 3) & 63;
    int grp  = i >> 9;                       // s*2 + t
    int t = grp & 1, s = grp >> 1;
    int kc = s * 32 + ((lane >> 4) << 3) + j;
    int o  = t * 16 + (lane & 15);
    int c = kc & 127, k = kc >> 7;
    float v = (o < 27) ? wcomb[k * 3456 + o * 128 + c] : 0.f;
    wC[i] = f2h(v);
}

// ---------------------------------------------------------------------------
// Swizzle 8 projection matrices [O][128] into hi/lo bf16 A-fragment planes.
// ---------------------------------------------------------------------------
__global__ __launch_bounds__(256) void setup_projA(
    const float* __restrict__ s0, const float* __restrict__ s1,
    const float* __restrict__ s2, const float* __restrict__ s3,
    const float* __restrict__ s4, const float* __restrict__ s5,
    const float* __restrict__ s6, const float* __restrict__ s7,
    unsigned short* __restrict__ dst)
{
    const int Os[8]   = {20, 80, 150, 150, 210, 210, 308, 308};
    const int nOt[8]  = {2, 5, 10, 10, 14, 14, 20, 20};
    const int tOff[8] = {0, 4096, 14336, 34816, 55296, 83968, 112640, 153600};
    const int dOff[8] = {0, 8192, 28672, 69632, 110592, 167936, 225280, 307200};
    int tid = blockIdx.x * 256 + threadIdx.x;
    if (tid >= 194560) return;
    int m = 0;
    #pragma unroll
    for (int q = 1; q < 8; ++q) if (tid >= tOff[q]) m = q;
    const float* src;
    switch (m) {
        case 0: src = s0; break; case 1: src = s1; break;
        case 2: src = s2; break; case 3: src = s3; break;
        case 4: src = s4; break; case 5: src = s5; break;
        case 6: src = s6; break; default: src = s7; break;
    }
    int i = tid - tOff[m];
    int j    = i & 7;
    int lane = (i >> 3) & 63;
    int s    = (i >> 9) & 3;
    int ot   = i >> 11;
    int o = ot * 16 + (lane & 15);
    int c = s * 32 + ((lane >> 4) << 3) + j;
    float v = (o < Os[m]) ? src[o * 128 + c] : 0.f;
    unsigned short h = f2bf(v);
    unsigned short l = f2bf(v - bf2f(h));
    const int hiSize = nOt[m] * 2048;
    dst[dOff[m] + i] = h;
    dst[dOff[m] + hiSize + i] = l;
}

// ---------------------------------------------------------------------------
// conv_offm, 512-thread version (8 waves): was latency-bound at 4 waves/SIMD.
// Gather: half-wave float4 (32 lanes = 128 ch), wave w covers px 2w, 2w+1.
// MFMA: wave = (t = wid&1, kq = wid>>1), 9 K-steps each; 4-way K-reduction
// through recycled LDS; 16-lane epilogue does softmax + offset assembly.
// 37.1 KB LDS -> 4 blocks/CU x 8 waves = 32 waves/CU (needs VGPR <= 64).
// ---------------------------------------------------------------------------
__global__ __launch_bounds__(512, 8) void conv_offm(
    const float* __restrict__ x, const unsigned short* __restrict__ wC,
    const float* __restrict__ bcomb, float* __restrict__ offm)
{
    __shared__ unsigned short smp[16 * 1160];   // 37120 B
    float* red  = (float*)smp;                  // recycled: [3][2][16][16] = 1536 f
    float* vals = red + 1536;                   // recycled: [16][33]       = 528 f

    const int lane = threadIdx.x & 63;
    const int wid  = threadIdx.x >> 6;          // 0..7
    const int gp0  = blockIdx.x * 16;
    const int half = lane >> 5;
    const int cl   = lane & 31;                 // channel-quad index
    const float4* x4 = (const float4*)x;

    // ---- gather: wave wid handles pixels 2*wid + half ----
    {
        const int pl = wid * 2 + half;
        const int gp = gp0 + pl;
        const int h0 = gp >> 7, w0 = gp & 127;
        unsigned* dstq = (unsigned*)smp + pl * 580 + cl * 2;
        #pragma unroll
        for (int k = 0; k < 9; ++k) {
            const int ny = h0 + k / 3 - 1;
            const int nx = w0 + k % 3 - 1;
            const int cy = min(max(ny, 0), 127);
            const int cx = min(max(nx, 0), 127);
            const float4 v = x4[(((cy << 7) + cx) << 5) + cl];
            const bool ok = ((unsigned)ny < 128u) & ((unsigned)nx < 128u);
            unsigned d0 = (unsigned)f2h(v.x) | ((unsigned)f2h(v.y) << 16);
            unsigned d1 = (unsigned)f2h(v.z) | ((unsigned)f2h(v.w) << 16);
            d0 = ok ? d0 : 0u;
            d1 = ok ? d1 : 0u;
            *(uint2*)(dstq + k * 64) = make_uint2(d0, d1);
        }
    }
    __syncthreads();

    // ---- MFMA: wave = (t = wid&1, kq = wid>>1), 9 K-steps each ----
    const int t    = wid & 1;
    const int kq   = wid >> 1;
    const int mrow = lane & 15;
    const int quad = lane >> 4;
    floatx4 acc = {0.f, 0.f, 0.f, 0.f};
    const unsigned short* arow = smp + mrow * 1160 + quad * 8;
    #pragma unroll
    for (int j = 0; j < 9; ++j) {
        const int s = kq * 9 + j;
        const f16x8 a = *(const f16x8*)(arow + s * 32);
        const f16x8 b = *(const f16x8*)(wC + (((s * 2 + t) * 64 + lane) << 3));
        acc = __builtin_amdgcn_mfma_f32_16x16x32_f16(a, b, acc, 0, 0, 0);
    }
    __syncthreads();   // all smp reads done; safe to recycle as red/vals

    // D: row (pixel) = quad*4+r, col (channel) = lane&15
    if (kq > 0) {
        #pragma unroll
        for (int r = 0; r < 4; ++r)
            red[(((kq - 1) * 2 + t) << 8) + (quad * 4 + r) * 16 + mrow] = acc[r];
    }
    __syncthreads();
    if (kq == 0) {
        #pragma unroll
        for (int r = 0; r < 4; ++r) {
            const int rc = (quad * 4 + r) * 16 + mrow;
            const float sv = acc[r] + red[(t << 8) + rc]
                           + red[((2 + t) << 8) + rc] + red[((4 + t) << 8) + rc];
            vals[(quad * 4 + r) * 33 + t * 16 + mrow] = sv;
        }
    }
    __syncthreads();

    // ---- epilogue: lane p < 16 handles pixel p ----
    if (threadIdx.x < 16) {
        const int p  = threadIdx.x;
        const int gp = gp0 + p;
        const int hh = gp >> 7, ww = gp & 127;
        const float* vp = vals + p * 33;
        float e[9], se = 0.f, mx = -1e30f;
        #pragma unroll
        for (int k = 0; k < 9; ++k) {
            e[k] = vp[18 + k] + bcomb[18 + k];
            mx = fmaxf(mx, e[k]);
        }
        #pragma unroll
        for (int k = 0; k < 9; ++k) { e[k] = expf(e[k] - mx); se += e[k]; }
        const float inv = 1.f / se;
        float* obp = offm + gp * 27;
        #pragma unroll
        for (int k = 0; k < 9; ++k) {
            obp[k]      = (float)(hh - 1 + k / 3) + vp[2 * k]     + bcomb[2 * k];
            obp[9 + k]  = (float)(ww - 1 + k % 3) + vp[2 * k + 1] + bcomb[2 * k + 1];
            obp[18 + k] = e[k] * inv;
        }
    }
}

// ---------------------------------------------------------------------------
// deform, 512-thread version (8 waves). Gather: half-wave float4, wave w
// covers px 2w, 2w+1; branchless corner clamp with validity folded into the
// bilinear weights. MFMA: wave = (tq = wid&3 out-pair, kh = wid>>2 K-half),
// 36 MFMA each; K-reduction through recycled LDS; kh=0 waves store + fused
// per-channel sum/sumsq stats. 32 waves/CU target (VGPR <= 64).
// ---------------------------------------------------------------------------
__global__ __launch_bounds__(512, 8) void deform_kernel(
    const float* __restrict__ x, const float* __restrict__ offm,
    const unsigned short* __restrict__ wBu, const float* __restrict__ cb,
    float* __restrict__ y, float* __restrict__ st)
{
    __shared__ unsigned short smp[16 * 1160];   // 37120 B
    float* red = (float*)smp;                   // recycled: [8][16][16] = 2048 f

    const int lane = threadIdx.x & 63;
    const int wid  = threadIdx.x >> 6;          // 0..7
    const int gp0  = blockIdx.x * 16;
    const int half = lane >> 5;
    const int cl   = lane & 31;
    const float4* x4 = (const float4*)x;

    // ---- phase 1: wave wid gathers pixels 2*wid + half ----
    {
        const int pl = wid * 2 + half;
        const float* ob = offm + (gp0 + pl) * 27;
        unsigned* dstq = (unsigned*)smp + pl * 580 + cl * 2;
        #pragma unroll
        for (int k = 0; k < 9; ++k) {
            const float py = ob[k], px = ob[9 + k], mk = ob[18 + k];
            const float y0f = floorf(py), x0f = floorf(px);
            const int iy0 = (int)y0f, ix0 = (int)x0f;
            const float wy1 = py - y0f, wy0 = 1.f - wy1;
            const float wx1 = px - x0f, wx0 = 1.f - wx1;
            const int cy0 = min(max(iy0, 0), 127);
            const int cy1 = min(max(iy0 + 1, 0), 127);
            const int cx0 = min(max(ix0, 0), 127);
            const int cx1 = min(max(ix0 + 1, 0), 127);
            const float vy0 = ((unsigned)iy0       < 128u) ? 1.f : 0.f;
            const float vy1 = ((unsigned)(iy0 + 1) < 128u) ? 1.f : 0.f;
            const float vx0 = ((unsigned)ix0       < 128u) ? 1.f : 0.f;
            const float vx1 = ((unsigned)(ix0 + 1) < 128u) ? 1.f : 0.f;
            const float w00 = wy0 * wx0 * vy0 * vx0 * mk;
            const float w01 = wy0 * wx1 * vy0 * vx1 * mk;
            const float w10 = wy1 * wx0 * vy1 * vx0 * mk;
            const float w11 = wy1 * wx1 * vy1 * vx1 * mk;
            const float4 g00 = x4[(((cy0 << 7) + cx0) << 5) + cl];
            const float4 g01 = x4[(((cy0 << 7) + cx1) << 5) + cl];
            const float4 g10 = x4[(((cy1 << 7) + cx0) << 5) + cl];
            const float4 g11 = x4[(((cy1 << 7) + cx1) << 5) + cl];
            const float s0 = fmaf(w00, g00.x, fmaf(w01, g01.x, fmaf(w10, g10.x, w11 * g11.x)));
            const float s1 = fmaf(w00, g00.y, fmaf(w01, g01.y, fmaf(w10, g10.y, w11 * g11.y)));
            const float s2 = fmaf(w00, g00.z, fmaf(w01, g01.z, fmaf(w10, g10.z, w11 * g11.z)));
            const float s3 = fmaf(w00, g00.w, fmaf(w01, g01.w, fmaf(w10, g10.w, w11 * g11.w)));
            const unsigned d0 = (unsigned)f2h(s0) | ((unsigned)f2h(s1) << 16);
            const unsigned d1 = (unsigned)f2h(s2) | ((unsigned)f2h(s3) << 16);
            *(uint2*)(dstq + k * 64) = make_uint2(d0, d1);
        }
    }
    __syncthreads();

    // ---- phase 2: MFMA. wave = (tq = wid&3, kh = wid>>2) ----
    const int tq = wid & 3;
    const int kh = wid >> 2;
    const int t0 = tq * 2, t1 = tq * 2 + 1;
    const int mrow = lane & 15;
    const int quad = lane >> 4;
    floatx4 acc0 = {0.f, 0.f, 0.f, 0.f};
    floatx4 acc1 = {0.f, 0.f, 0.f, 0.f};
    const unsigned short* arow = smp + mrow * 1160 + quad * 8;
    #pragma unroll 6
    for (int j = 0; j < 18; ++j) {
        const int s = kh * 18 + j;
        const f16x8 a  = *(const f16x8*)(arow + s * 32);
        const f16x8 b0 = *(const f16x8*)(wBu + (((s * 8 + t0) * 64 + lane) << 3));
        const f16x8 b1 = *(const f16x8*)(wBu + (((s * 8 + t1) * 64 + lane) << 3));
        acc0 = __builtin_amdgcn_mfma_f32_16x16x32_f16(a, b0, acc0, 0, 0, 0);
        acc1 = __builtin_amdgcn_mfma_f32_16x16x32_f16(a, b1, acc1, 0, 0, 0);
    }
    __syncthreads();   // all smp reads done; safe to recycle as red

    if (kh == 1) {
        #pragma unroll
        for (int r = 0; r < 4; ++r) {
            const int rc = (quad * 4 + r) * 16 + mrow;
            red[(t0 << 8) + rc] = acc0[r];
            red[(t1 << 8) + rc] = acc1[r];
        }
    }
    __syncthreads();
    if (kh == 0) {
        const int n0 = t0 * 16 + mrow, n1 = t1 * 16 + mrow;
        const float bias0 = cb[n0], bias1 = cb[n1];
        float s0 = 0.f, q0 = 0.f, s1 = 0.f, q1 = 0.f;
        #pragma unroll
        for (int r = 0; r < 4; ++r) {
            const int rc = (quad * 4 + r) * 16 + mrow;
            const float v0 = acc0[r] + red[(t0 << 8) + rc] + bias0;
            const float v1 = acc1[r] + red[(t1 << 8) + rc] + bias1;
            float* yr = y + (size_t)(gp0 + quad * 4 + r) * 128;
            yr[n0] = v0;
            yr[n1] = v1;
            s0 += v0; q0 = fmaf(v0, v0, q0);
            s1 += v1; q1 = fmaf(v1, v1, q1);
        }
        // channel n0/n1 owned by exactly one wave; reduce over the 4 quads
        s0 += __shfl_xor(s0, 16); q0 += __shfl_xor(q0, 16);
        s1 += __shfl_xor(s1, 16); q1 += __shfl_xor(q1, 16);
        s0 += __shfl_xor(s0, 32); q0 += __shfl_xor(q0, 32);
        s1 += __shfl_xor(s1, 32); q1 += __shfl_xor(q1, 32);
        if (quad == 0) {
            atomicAdd(&st[n0], s0);
            atomicAdd(&st[n1], s1);
            atomicAdd(&st[128 + n0], q0);
            atomicAdd(&st[128 + n1], q1);
        }
    }
}

__global__ __launch_bounds__(256) void norm_relu(
    float* __restrict__ y, const float* __restrict__ stats,
    const float* __restrict__ bg, const float* __restrict__ bb)
{
    const int g = blockIdx.x * 256 + threadIdx.x;   // grid 2048 -> 524288 threads
    const int c0 = (g << 2) & 127;
    float4 v = ((const float4*)y)[g];
    float sc[4], sh[4];
    #pragma unroll
    for (int j = 0; j < 4; ++j) {
        const int c = c0 + j;
        const float mean = stats[c] * (1.f / 16384.f);
        const float var  = stats[128 + c] * (1.f / 16384.f) - mean * mean;
        const float rstd = rsqrtf(var + EPS);
        sc[j] = bg[c] * rstd;
        sh[j] = bb[c] - mean * sc[j];
    }
    v.x = fmaxf(fmaf(v.x, sc[0], sh[0]), 0.f);
    v.y = fmaxf(fmaf(v.y, sc[1], sh[1]), 0.f);
    v.z = fmaxf(fmaf(v.z, sc[2], sh[2]), 0.f);
    v.w = fmaxf(fmaf(v.w, sc[3], sh[3]), 0.f);
    ((float4*)y)[g] = v;
}

// ---------------------------------------------------------------------------
// 1x1 projection as hi/lo-split bf16 MFMA GEMM (fp32-accurate).
// blockIdx.y splits the out-tile dim (was 1 block/CU at grid 256).
// ---------------------------------------------------------------------------
__global__ __launch_bounds__(256) void proj_kernel(
    const float* __restrict__ xin, const unsigned short* __restrict__ aP,
    float* __restrict__ out, int O, int hiSize, int accum)
{
    __shared__ unsigned short sh[64 * 136];
    __shared__ unsigned short sl[64 * 136];
    const int gp0 = blockIdx.x * 64;

    // stage 64 px x 128 c, split into hi/lo bf16 (dword-packed writes)
    for (int i = threadIdx.x; i < 4096; i += 256) {
        const int p = i >> 6, c2 = (i & 63) * 2;
        const float2 v = *(const float2*)(xin + (gp0 + p) * 128 + c2);
        const unsigned short h0 = f2bf(v.x), h1 = f2bf(v.y);
        const unsigned short l0 = f2bf(v.x - bf2f(h0)), l1 = f2bf(v.y - bf2f(h1));
        ((unsigned*)sh)[p * 68 + (c2 >> 1)] = (unsigned)h0 | ((unsigned)h1 << 16);
        ((unsigned*)sl)[p * 68 + (c2 >> 1)] = (unsigned)l0 | ((unsigned)l1 << 16);
    }
    __syncthreads();

    const int lane = threadIdx.x & 63;
    const int wid  = threadIdx.x >> 6;
    const int quad = lane >> 4;
    const int nrow = lane & 15;
    const int nOt  = (O + 15) >> 4;
    const int ot   = blockIdx.y * 4 + wid;

    if (ot < nOt) {
        bf16x8 Ah[4], Al[4];
        #pragma unroll
        for (int s = 0; s < 4; ++s) {
            const int idx = ((ot * 4 + s) * 64 + lane) * 8;
            Ah[s] = *(const bf16x8*)(aP + idx);
            Al[s] = *(const bf16x8*)(aP + hiSize + idx);
        }
        #pragma unroll
        for (int pt = 0; pt < 4; ++pt) {
            floatx4 acc = {0.f, 0.f, 0.f, 0.f};
            const int roff = (pt * 16 + nrow) * 136 + quad * 8;
            #pragma unroll
            for (int s = 0; s < 4; ++s) {
                const bf16x8 Bh = *(const bf16x8*)(sh + roff + s * 32);
                const bf16x8 Bl = *(const bf16x8*)(sl + roff + s * 32);
                acc = __builtin_amdgcn_mfma_f32_16x16x32_bf16(Ah[s], Bh, acc, 0, 0, 0);
                acc = __builtin_amdgcn_mfma_f32_16x16x32_bf16(Al[s], Bh, acc, 0, 0, 0);
                acc = __builtin_amdgcn_mfma_f32_16x16x32_bf16(Ah[s], Bl, acc, 0, 0, 0);
            }
            #pragma unroll
            for (int r = 0; r < 4; ++r) {
                const int o = ot * 16 + quad * 4 + r;
                if (o < O) {
                    float* dst = out + (size_t)o * NPIX + gp0 + pt * 16 + nrow;
                    *dst = accum ? (*dst + acc[r]) : acc[r];
                }
            }
        }
    }
}

// ---------------------------------------------------------------------------
// Final layernorm over the W axis: one wave per (c,h) row of 128.
// ---------------------------------------------------------------------------
__global__ __launch_bounds__(256) void final_ln(
    float* __restrict__ out, const float* __restrict__ lnw,
    const float* __restrict__ lnb)
{
    const int lane = threadIdx.x & 63;
    const int wid  = threadIdx.x >> 6;
    const int row  = blockIdx.x * 4 + wid;          // 98304 rows
    float* rp = out + row * 128;
    const float v0 = rp[lane], v1 = rp[lane + 64];
    float s = v0 + v1;
    float q = v0 * v0 + v1 * v1;
    #pragma unroll
    for (int m = 32; m; m >>= 1) {
        s += __shfl_xor(s, m);
        q += __shfl_xor(q, m);
    }
    const float mean = s * (1.f / 128.f);
    const float var  = q * (1.f / 128.f) - mean * mean;
    const float rstd = rsqrtf(var + EPS);
    rp[lane]      = (v0 - mean) * rstd * lnw[lane]      + lnb[lane];
    rp[lane + 64] = (v1 - mean) * rstd * lnw[lane + 64] + lnb[lane + 64];
}

// ---------------------------------------------------------------------------
extern "C" void kernel_launch(void* const* d_in, const int* in_sizes, int n_in,
                              void* d_out, int out_size, void* d_ws, size_t ws_size,
                              hipStream_t stream)
{
    const float* xin[5];
    for (int i = 0; i < 5; ++i) xin[i] = (const float*)d_in[i];
    const float* b_cw[2] = {(const float*)d_in[5],  (const float*)d_in[11]};
    const float* b_cb[2] = {(const float*)d_in[6],  (const float*)d_in[12]};
    const float* b_ow[2] = {(const float*)d_in[7],  (const float*)d_in[13]};
    const float* b_mw[2] = {(const float*)d_in[8],  (const float*)d_in[14]};
    const float* b_bg[2] = {(const float*)d_in[9],  (const float*)d_in[15]};
    const float* b_bb[2] = {(const float*)d_in[10], (const float*)d_in[16]};
    const float* pw[8];
    for (int i = 0; i < 8; ++i) pw[i] = (const float*)d_in[17 + i];
    const float* lnw = (const float*)d_in[25];
    const float* lnb = (const float*)d_in[26];

    float* W = (float*)d_ws;
    float* out = (float*)d_out;
    unsigned short* wB = (unsigned short*)(W + OFF_WB);
    unsigned short* wC = (unsigned short*)(W + OFF_WC);
    unsigned short* aP = (unsigned short*)(W + OFF_APROJ);

    hipMemsetAsync(W + OFF_STATS, 0, 2560 * sizeof(float), stream);

    setup_conv<<<704, 256, 0, stream>>>(b_cw[0], b_cb[0], b_ow[0], b_mw[0],
        W + OFF_WCOMB, W + OFF_BCOMB, wB);
    setup_conv<<<704, 256, 0, stream>>>(b_cw[1], b_cb[1], b_ow[1], b_mw[1],
        W + OFF_WCOMB + 31104, W + OFF_BCOMB + 32, wB + 147456);
    setup_convfrag<<<144, 256, 0, stream>>>(W + OFF_WCOMB, wC);
    setup_convfrag<<<144, 256, 0, stream>>>(W + OFF_WCOMB + 31104, wC + 36864);
    setup_projA<<<760, 256, 0, stream>>>(pw[0], pw[1], pw[2], pw[3],
        pw[4], pw[5], pw[6], pw[7], aP);

    static const int Obase[5] = {0, 20, 100, 250, 460};
    static const int Ocnt[5]  = {20, 80, 150, 210, 308};
    // A-frag plane offsets (ushort) and hi-plane sizes
    static const int aOffA[5] = {0, 8192, 28672, 110592, 225280};      // c1,c2,c3a,c4a,c5a
    static const int aOffB[5] = {0, 0, 69632, 167936, 307200};         // c3b,c4b,c5b
    static const int hiSz[5]  = {4096, 10240, 20480, 28672, 40960};
    static const int yGrd[5]  = {1, 2, 3, 4, 5};                       // ceil(nOt/4)

    for (int img = 0; img < 5; ++img) {
        for (int blk = 0; blk < 2; ++blk) {
            const float* xb = (blk == 0) ? xin[img] : (W + OFF_BUFA);
            float* yb = (blk == 0) ? (W + OFF_BUFA) : (W + OFF_BUFB);
            float* st = W + OFF_STATS + (img * 2 + blk) * 256;
            conv_offm<<<1024, 512, 0, stream>>>(
                xb, wC + blk * 36864, W + OFF_BCOMB + blk * 32, W + OFF_OFFM);
            deform_kernel<<<1024, 512, 0, stream>>>(
                xb, W + OFF_OFFM, wB + blk * 147456, b_cb[blk], yb, st);
            norm_relu<<<2048, 256, 0, stream>>>(yb, st, b_bg[blk], b_bb[blk]);
        }
        float* outb = out + (size_t)Obase[img] * NPIX;
        proj_kernel<<<dim3(256, yGrd[img]), 256, 0, stream>>>(
            W + OFF_BUFB, aP + aOffA[img], outb, Ocnt[img], hiSz[img], 0);
        if (img >= 2)
            proj_kernel<<<dim3(256, yGrd[img]), 256, 0, stream>>>(
                xin[img], aP + aOffB[img], outb, Ocnt[img], hiSz[img], 1);
    }
    final_ln<<<24576, 256, 0, stream>>>(out, lnw, lnb);
}

// Round 3
// 803.282 us; speedup vs baseline: 1.3187x; 1.0014x over previous
//
#include <hip/hip_runtime.h>
#include <math.h>

// Problem constants
#define HH 128
#define WW 128
#define CC 128
#define KK 9
#define NPIX 16384           // H*W
#define NELEM 2097152        // NPIX*C
#define EPS 1e-5f

// Workspace layout (float offsets)
#define OFF_WCOMB 0          // [2][9][27][128] fp32      = 62208
#define OFF_BCOMB 62208      // [2][32] fp32              = 64
#define OFF_WB    62272      // fp16 B-frag deform w: 2*147456 ushort = 147456 floats
#define OFF_WC    209728     // fp16 B-frag conv w:   2*36864 ushort  = 36864 floats
#define OFF_APROJ 246592     // hi/lo bf16 A-frag proj w: 389120 ushort = 194560 floats
#define OFF_OFFA  441152     // uint2[16384*9] packed corner idx = 294912 floats
#define OFF_OFFW  736064     // float4[16384*9] weights          = 589824 floats
#define OFF_BUFA  1325888    // [16384][128]              = 2097152
#define OFF_BUFB  3423040    // [16384][128]              = 2097152
#define OFF_STATS 5520192    // [10][2][128]              = 2560
#define WS_FLOATS 5522752    // ~22.1 MB

typedef __bf16    bf16x8 __attribute__((ext_vector_type(8)));
typedef _Float16  f16x8  __attribute__((ext_vector_type(8)));
typedef float     floatx4 __attribute__((ext_vector_type(4)));

__device__ __forceinline__ unsigned short f2bf(float f) {
    unsigned u = __float_as_uint(f);
    return (unsigned short)((u + 0x7FFF + ((u >> 16) & 1)) >> 16);   // RNE
}
__device__ __forceinline__ float bf2f(unsigned short h) {
    return __uint_as_float(((unsigned)h) << 16);
}
__device__ __forceinline__ unsigned short f2h(float f) {
    _Float16 h = (_Float16)f;                                        // v_cvt_f16_f32 (RNE)
    return __builtin_bit_cast(unsigned short, h);
}

// ---------------------------------------------------------------------------
// Setup: compose [ow;mw] @ cw -> 27-ch conv weights (layout [k][o][c]),
// composed bias, and swizzle cw into fp16 MFMA B-fragment order (deform):
//   kc = s*32 + (lane>>4)*8 + j (kc = k*128+c), o = t*16 + (lane&15)
// ---------------------------------------------------------------------------
__global__ __launch_bounds__(256) void setup_conv(
    const float* __restrict__ cw, const float* __restrict__ cb,
    const float* __restrict__ ow, const float* __restrict__ mw,
    float* __restrict__ wcomb, float* __restrict__ bcomb,
    unsigned short* __restrict__ wBu)
{
    int tid = blockIdx.x * 256 + threadIdx.x;
    if (tid < 31104) {
        int c = tid & 127;
        int o = (tid >> 7) % 27;
        int k = tid / 3456;                  // k in [0,9)
        const float* sel = (o < 18) ? (ow + o * 128) : (mw + (o - 18) * 128);
        float v = 0.f;
        for (int cp = 0; cp < 128; ++cp)
            v = fmaf(sel[cp], cw[cp * 1152 + c * 9 + k], v);
        wcomb[tid] = v;                      // wcomb[k][o][c]
    } else if (tid < 31104 + 27) {
        int o = tid - 31104;
        const float* sel = (o < 18) ? (ow + o * 128) : (mw + (o - 18) * 128);
        float v = 0.f;
        for (int cp = 0; cp < 128; ++cp)
            v = fmaf(sel[cp], cb[cp], v);
        bcomb[o] = v;
    } else if (tid >= 32768 && tid < 32768 + 147456) {
        int i = tid - 32768;
        int j    = i & 7;
        int lane = (i >> 3) & 63;
        int t    = (i >> 9) & 7;
        int s    = i >> 12;                  // 0..35
        int kc   = s * 32 + ((lane >> 4) << 3) + j;
        int o    = t * 16 + (lane & 15);
        wBu[i] = f2h(cw[o * 1152 + (kc & 127) * 9 + (kc >> 7)]);
    }
}

// ---------------------------------------------------------------------------
// Swizzle composed conv weights wcomb[k][o][c] into fp16 B-frag order for the
// conv_offm MFMA (27 outputs padded to 32 -> 2 out-tiles).
// ---------------------------------------------------------------------------
__global__ __launch_bounds__(256) void setup_convfrag(
    const float* __restrict__ wcomb, unsigned short* __restrict__ wC)
{
    int i = blockIdx.x * 256 + threadIdx.x;
    if (i >= 36864) return;
    int j    = i & 7;
    int lane = (i >> 3) & 63;
    int grp  = i >> 9;                       // s*2 + t
    int t = grp & 1, s = grp >> 1;
    int kc = s * 32 + ((lane >> 4) << 3) + j;
    int o  = t * 16 + (lane & 15);
    int c = kc & 127, k = kc >> 7;
    float v = (o < 27) ? wcomb[k * 3456 + o * 128 + c] : 0.f;
    wC[i] = f2h(v);
}

// ---------------------------------------------------------------------------
// Swizzle 8 projection matrices [O][128] into hi/lo bf16 A-fragment planes.
// ---------------------------------------------------------------------------
__global__ __launch_bounds__(256) void setup_projA(
    const float* __restrict__ s0, const float* __restrict__ s1,
    const float* __restrict__ s2, const float* __restrict__ s3,
    const float* __restrict__ s4, const float* __restrict__ s5,
    const float* __restrict__ s6, const float* __restrict__ s7,
    unsigned short* __restrict__ dst)
{
    const int Os[8]   = {20, 80, 150, 150, 210, 210, 308, 308};
    const int nOt[8]  = {2, 5, 10, 10, 14, 14, 20, 20};
    const int tOff[8] = {0, 4096, 14336, 34816, 55296, 83968, 112640, 153600};
    const int dOff[8] = {0, 8192, 28672, 69632, 110592, 167936, 225280, 307200};
    int tid = blockIdx.x * 256 + threadIdx.x;
    if (tid >= 194560) return;
    int m = 0;
    #pragma unroll
    for (int q = 1; q < 8; ++q) if (tid >= tOff[q]) m = q;
    const float* src;
    switch (m) {
        case 0: src = s0; break; case 1: src = s1; break;
        case 2: src = s2; break; case 3: src = s3; break;
        case 4: src = s4; break; case 5: src = s5; break;
        case 6: src = s6; break; default: src = s7; break;
    }
    int i = tid - tOff[m];
    int j    = i & 7;
    int lane = (i >> 3) & 63;
    int s    = (i >> 9) & 3;
    int ot   = i >> 11;
    int o = ot * 16 + (lane & 15);
    int c = s * 32 + ((lane >> 4) << 3) + j;
    float v = (o < Os[m]) ? src[o * 128 + c] : 0.f;
    unsigned short h = f2bf(v);
    unsigned short l = f2bf(v - bf2f(h));
    const int hiSize = nOt[m] * 2048;
    dst[dOff[m] + i] = h;
    dst[dOff[m] + hiSize + i] = l;
}

// ---------------------------------------------------------------------------
// conv_offm, 512 threads (8 waves). Gather: half-wave float4 (32 lanes =
// 128 ch), static clipped 3x3 neighborhood. MFMA: wave = (t = wid&1,
// kq = wid>>1), 9 K-steps with explicit B prefetch rotation; 4-way
// K-reduction through recycled LDS. Epilogue: 16 lanes do softmax masks,
// then 144 threads emit packed bilinear gather descriptors (corner indices
// + mask-folded weights) so deform_kernel needs no address math.
// ---------------------------------------------------------------------------
__global__ __launch_bounds__(512, 8) void conv_offm(
    const float* __restrict__ x, const unsigned short* __restrict__ wC,
    const float* __restrict__ bcomb, unsigned* __restrict__ offa,
    float* __restrict__ offw)
{
    __shared__ unsigned short smp[16 * 1160];   // 37120 B
    float* red  = (float*)smp;                  // recycled: [3][2][16][16] = 1536 f
    float* vals = red + 1536;                   // recycled: [16][33]       = 528 f
    float* maskL = red;                         // recycled again: [16][9]

    const int lane = threadIdx.x & 63;
    const int wid  = threadIdx.x >> 6;          // 0..7
    const int gp0  = blockIdx.x * 16;
    const int half = lane >> 5;
    const int cl   = lane & 31;                 // channel-quad index
    const float4* x4 = (const float4*)x;

    // ---- gather: wave wid handles pixels 2*wid + half ----
    {
        const int pl = wid * 2 + half;
        const int gp = gp0 + pl;
        const int h0 = gp >> 7, w0 = gp & 127;
        unsigned* dstq = (unsigned*)smp + pl * 580 + cl * 2;
        #pragma unroll
        for (int k = 0; k < 9; ++k) {
            const int ny = h0 + k / 3 - 1;
            const int nx = w0 + k % 3 - 1;
            const int cy = min(max(ny, 0), 127);
            const int cx = min(max(nx, 0), 127);
            const float4 v = x4[(((cy << 7) + cx) << 5) + cl];
            const bool ok = ((unsigned)ny < 128u) & ((unsigned)nx < 128u);
            unsigned d0 = (unsigned)f2h(v.x) | ((unsigned)f2h(v.y) << 16);
            unsigned d1 = (unsigned)f2h(v.z) | ((unsigned)f2h(v.w) << 16);
            d0 = ok ? d0 : 0u;
            d1 = ok ? d1 : 0u;
            *(uint2*)(dstq + k * 64) = make_uint2(d0, d1);
        }
    }
    __syncthreads();

    // ---- MFMA: wave = (t = wid&1, kq = wid>>1), 9 K-steps each ----
    const int t    = wid & 1;
    const int kq   = wid >> 1;
    const int mrow = lane & 15;
    const int quad = lane >> 4;
    floatx4 acc = {0.f, 0.f, 0.f, 0.f};
    const unsigned short* arow = smp + mrow * 1160 + quad * 8;
    const unsigned short* bbase = wC + t * 512 + (lane << 3);
    f16x8 b = *(const f16x8*)(bbase + (kq * 9) * 1024);
    #pragma unroll
    for (int j = 0; j < 9; ++j) {
        const int s = kq * 9 + j;
        f16x8 nb;
        if (j < 8) nb = *(const f16x8*)(bbase + (s + 1) * 1024);
        const f16x8 a = *(const f16x8*)(arow + s * 32);
        acc = __builtin_amdgcn_mfma_f32_16x16x32_f16(a, b, acc, 0, 0, 0);
        if (j < 8) b = nb;
    }
    __syncthreads();   // all smp reads done; safe to recycle as red/vals

    // D: row (pixel) = quad*4+r, col (channel) = lane&15
    if (kq > 0) {
        #pragma unroll
        for (int r = 0; r < 4; ++r)
            red[(((kq - 1) * 2 + t) << 8) + (quad * 4 + r) * 16 + mrow] = acc[r];
    }
    __syncthreads();
    if (kq == 0) {
        #pragma unroll
        for (int r = 0; r < 4; ++r) {
            const int rc = (quad * 4 + r) * 16 + mrow;
            const float sv = acc[r] + red[(t << 8) + rc]
                           + red[((2 + t) << 8) + rc] + red[((4 + t) << 8) + rc];
            vals[(quad * 4 + r) * 33 + t * 16 + mrow] = sv;
        }
    }
    __syncthreads();

    // ---- epilogue A: lanes < 16 compute softmax masks into maskL ----
    if (threadIdx.x < 16) {
        const int p = threadIdx.x;
        const float* vp = vals + p * 33;
        float e[9], se = 0.f, mx = -1e30f;
        #pragma unroll
        for (int k = 0; k < 9; ++k) {
            e[k] = vp[18 + k] + bcomb[18 + k];
            mx = fmaxf(mx, e[k]);
        }
        #pragma unroll
        for (int k = 0; k < 9; ++k) { e[k] = expf(e[k] - mx); se += e[k]; }
        const float inv = 1.f / se;
        #pragma unroll
        for (int k = 0; k < 9; ++k) maskL[p * 9 + k] = e[k] * inv;
    }
    __syncthreads();

    // ---- epilogue B: 144 threads emit packed gather descriptors ----
    if (threadIdx.x < 144) {
        const int p = threadIdx.x / 9;
        const int k = threadIdx.x - p * 9;
        const int gp = gp0 + p;
        const int hh = gp >> 7, ww = gp & 127;
        const float* vp = vals + p * 33;
        const float py = (float)(hh - 1 + k / 3) + vp[2 * k]     + bcomb[2 * k];
        const float px = (float)(ww - 1 + k % 3) + vp[2 * k + 1] + bcomb[2 * k + 1];
        const float mk = maskL[p * 9 + k];
        const float y0f = floorf(py), x0f = floorf(px);
        const int iy0 = (int)y0f, ix0 = (int)x0f;
        const float wy1 = py - y0f, wy0 = 1.f - wy1;
        const float wx1 = px - x0f, wx0 = 1.f - wx1;
        const int cy0 = min(max(iy0, 0), 127);
        const int cy1 = min(max(iy0 + 1, 0), 127);
        const int cx0 = min(max(ix0, 0), 127);
        const int cx1 = min(max(ix0 + 1, 0), 127);
        const float vy0 = ((unsigned)iy0       < 128u) ? 1.f : 0.f;
        const float vy1 = ((unsigned)(iy0 + 1) < 128u) ? 1.f : 0.f;
        const float vx0 = ((unsigned)ix0       < 128u) ? 1.f : 0.f;
        const float vx1 = ((unsigned)(ix0 + 1) < 128u) ? 1.f : 0.f;
        const float w00 = wy0 * wx0 * vy0 * vx0 * mk;
        const float w01 = wy0 * wx1 * vy0 * vx1 * mk;
        const float w10 = wy1 * wx0 * vy1 * vx0 * mk;
        const float w11 = wy1 * wx1 * vy1 * vx1 * mk;
        const unsigned i00 = (unsigned)((cy0 << 7) | cx0);
        const unsigned i01 = (unsigned)((cy0 << 7) | cx1);
        const unsigned i10 = (unsigned)((cy1 << 7) | cx0);
        const unsigned i11 = (unsigned)((cy1 << 7) | cx1);
        ((uint2*)offa)[(size_t)gp * 9 + k] =
            make_uint2(i00 | (i01 << 16), i10 | (i11 << 16));
        ((float4*)offw)[(size_t)gp * 9 + k] = make_float4(w00, w01, w10, w11);
    }
}

// ---------------------------------------------------------------------------
// deform, 512 threads (8 waves). Gather reads precomputed descriptors
// (addresses ready at entry -> all corner loads pipeline, no float->addr
// chain). MFMA: one wave = one out-tile (t = wid), full K = 36 steps with
// explicit B prefetch rotation. No cross-wave reduction, ONE barrier.
// Epilogue: store + fused per-channel sum/sumsq stats.
// ---------------------------------------------------------------------------
__global__ __launch_bounds__(512, 8) void deform_kernel(
    const float* __restrict__ x, const unsigned* __restrict__ offa,
    const float* __restrict__ offw, const unsigned short* __restrict__ wBu,
    const float* __restrict__ cb, float* __restrict__ y, float* __restrict__ st)
{
    __shared__ unsigned short smp[16 * 1160];   // 37120 B

    const int lane = threadIdx.x & 63;
    const int wid  = threadIdx.x >> 6;          // 0..7
    const int gp0  = blockIdx.x * 16;
    const int half = lane >> 5;
    const int cl   = lane & 31;
    const float4* x4 = (const float4*)x;

    // ---- phase 1: wave wid gathers pixels 2*wid + half ----
    {
        const int pl = wid * 2 + half;
        const size_t tb = (size_t)(gp0 + pl) * 9;
        const uint2*  ap = (const uint2*)offa + tb;
        const float4* wp = (const float4*)offw + tb;
        unsigned* dstq = (unsigned*)smp + pl * 580 + cl * 2;
        #pragma unroll
        for (int k = 0; k < 9; ++k) {
            const uint2  a = ap[k];
            const float4 w = wp[k];
            const int i00 = (int)(a.x & 0xFFFFu) << 5;
            const int i01 = (int)(a.x >> 16) << 5;
            const int i10 = (int)(a.y & 0xFFFFu) << 5;
            const int i11 = (int)(a.y >> 16) << 5;
            const float4 g00 = x4[i00 + cl];
            const float4 g01 = x4[i01 + cl];
            const float4 g10 = x4[i10 + cl];
            const float4 g11 = x4[i11 + cl];
            const float s0 = fmaf(w.x, g00.x, fmaf(w.y, g01.x, fmaf(w.z, g10.x, w.w * g11.x)));
            const float s1 = fmaf(w.x, g00.y, fmaf(w.y, g01.y, fmaf(w.z, g10.y, w.w * g11.y)));
            const float s2 = fmaf(w.x, g00.z, fmaf(w.y, g01.z, fmaf(w.z, g10.z, w.w * g11.z)));
            const float s3 = fmaf(w.x, g00.w, fmaf(w.y, g01.w, fmaf(w.z, g10.w, w.w * g11.w)));
            const unsigned d0 = (unsigned)f2h(s0) | ((unsigned)f2h(s1) << 16);
            const unsigned d1 = (unsigned)f2h(s2) | ((unsigned)f2h(s3) << 16);
            *(uint2*)(dstq + k * 64) = make_uint2(d0, d1);
        }
    }
    __syncthreads();

    // ---- phase 2: wave wid owns out-tile t = wid, full K (36 steps) ----
    const int mrow = lane & 15;
    const int quad = lane >> 4;
    const unsigned short* arow  = smp + mrow * 1160 + quad * 8;
    const unsigned short* bbase = wBu + wid * 512 + (lane << 3);
    floatx4 acc = {0.f, 0.f, 0.f, 0.f};
    f16x8 b = *(const f16x8*)(bbase);
    #pragma unroll
    for (int s = 0; s < 36; ++s) {
        f16x8 nb;
        if (s < 35) nb = *(const f16x8*)(bbase + (size_t)(s + 1) * 4096);
        const f16x8 a = *(const f16x8*)(arow + s * 32);
        acc = __builtin_amdgcn_mfma_f32_16x16x32_f16(a, b, acc, 0, 0, 0);
        if (s < 35) b = nb;
    }

    // ---- epilogue: store + per-channel stats (channel n = wid*16+mrow) ----
    const int n = wid * 16 + mrow;
    const float bias = cb[n];
    float ssum = 0.f, qsum = 0.f;
    #pragma unroll
    for (int r = 0; r < 4; ++r) {
        const float v = acc[r] + bias;
        y[(size_t)(gp0 + quad * 4 + r) * 128 + n] = v;
        ssum += v; qsum = fmaf(v, v, qsum);
    }
    ssum += __shfl_xor(ssum, 16); qsum += __shfl_xor(qsum, 16);
    ssum += __shfl_xor(ssum, 32); qsum += __shfl_xor(qsum, 32);
    if (quad == 0) {
        atomicAdd(&st[n], ssum);
        atomicAdd(&st[128 + n], qsum);
    }
}

__global__ __launch_bounds__(256) void norm_relu(
    float* __restrict__ y, const float* __restrict__ stats,
    const float* __restrict__ bg, const float* __restrict__ bb)
{
    const int g = blockIdx.x * 256 + threadIdx.x;   // grid 2048 -> 524288 threads
    const int c0 = (g << 2) & 127;
    float4 v = ((const float4*)y)[g];
    float sc[4], sh[4];
    #pragma unroll
    for (int j = 0; j < 4; ++j) {
        const int c = c0 + j;
        const float mean = stats[c] * (1.f / 16384.f);
        const float var  = stats[128 + c] * (1.f / 16384.f) - mean * mean;
        const float rstd = rsqrtf(var + EPS);
        sc[j] = bg[c] * rstd;
        sh[j] = bb[c] - mean * sc[j];
    }
    v.x = fmaxf(fmaf(v.x, sc[0], sh[0]), 0.f);
    v.y = fmaxf(fmaf(v.y, sc[1], sh[1]), 0.f);
    v.z = fmaxf(fmaf(v.z, sc[2], sh[2]), 0.f);
    v.w = fmaxf(fmaf(v.w, sc[3], sh[3]), 0.f);
    ((float4*)y)[g] = v;
}

// ---------------------------------------------------------------------------
// 1x1 projection as hi/lo-split bf16 MFMA GEMM (fp32-accurate).
// blockIdx.y splits the out-tile dim.
// ---------------------------------------------------------------------------
__global__ __launch_bounds__(256) void proj_kernel(
    const float* __restrict__ xin, const unsigned short* __restrict__ aP,
    float* __restrict__ out, int O, int hiSize, int accum)
{
    __shared__ unsigned short sh[64 * 136];
    __shared__ unsigned short sl[64 * 136];
    const int gp0 = blockIdx.x * 64;

    // stage 64 px x 128 c, split into hi/lo bf16 (dword-packed writes)
    for (int i = threadIdx.x; i < 4096; i += 256) {
        const int p = i >> 6, c2 = (i & 63) * 2;
        const float2 v = *(const float2*)(xin + (gp0 + p) * 128 + c2);
        const unsigned short h0 = f2bf(v.x), h1 = f2bf(v.y);
        const unsigned short l0 = f2bf(v.x - bf2f(h0)), l1 = f2bf(v.y - bf2f(h1));
        ((unsigned*)sh)[p * 68 + (c2 >> 1)] = (unsigned)h0 | ((unsigned)h1 << 16);
        ((unsigned*)sl)[p * 68 + (c2 >> 1)] = (unsigned)l0 | ((unsigned)l1 << 16);
    }
    __syncthreads();

    const int lane = threadIdx.x & 63;
    const int wid  = threadIdx.x >> 6;
    const int quad = lane >> 4;
    const int nrow = lane & 15;
    const int nOt  = (O + 15) >> 4;
    const int ot   = blockIdx.y * 4 + wid;

    if (ot < nOt) {
        bf16x8 Ah[4], Al[4];
        #pragma unroll
        for (int s = 0; s < 4; ++s) {
            const int idx = ((ot * 4 + s) * 64 + lane) * 8;
            Ah[s] = *(const bf16x8*)(aP + idx);
            Al[s] = *(const bf16x8*)(aP + hiSize + idx);
        }
        #pragma unroll
        for (int pt = 0; pt < 4; ++pt) {
            floatx4 acc = {0.f, 0.f, 0.f, 0.f};
            const int roff = (pt * 16 + nrow) * 136 + quad * 8;
            #pragma unroll
            for (int s = 0; s < 4; ++s) {
                const bf16x8 Bh = *(const bf16x8*)(sh + roff + s * 32);
                const bf16x8 Bl = *(const bf16x8*)(sl + roff + s * 32);
                acc = __builtin_amdgcn_mfma_f32_16x16x32_bf16(Ah[s], Bh, acc, 0, 0, 0);
                acc = __builtin_amdgcn_mfma_f32_16x16x32_bf16(Al[s], Bh, acc, 0, 0, 0);
                acc = __builtin_amdgcn_mfma_f32_16x16x32_bf16(Ah[s], Bl, acc, 0, 0, 0);
            }
            #pragma unroll
            for (int r = 0; r < 4; ++r) {
                const int o = ot * 16 + quad * 4 + r;
                if (o < O) {
                    float* dst = out + (size_t)o * NPIX + gp0 + pt * 16 + nrow;
                    *dst = accum ? (*dst + acc[r]) : acc[r];
                }
            }
        }
    }
}

// ---------------------------------------------------------------------------
// Final layernorm over the W axis: one wave per (c,h) row of 128.
// ---------------------------------------------------------------------------
__global__ __launch_bounds__(256) void final_ln(
    float* __restrict__ out, const float* __restrict__ lnw,
    const float* __restrict__ lnb)
{
    const int lane = threadIdx.x & 63;
    const int wid  = threadIdx.x >> 6;
    const int row  = blockIdx.x * 4 + wid;          // 98304 rows
    float* rp = out + row * 128;
    const float v0 = rp[lane], v1 = rp[lane + 64];
    float s = v0 + v1;
    float q = v0 * v0 + v1 * v1;
    #pragma unroll
    for (int m = 32; m; m >>= 1) {
        s += __shfl_xor(s, m);
        q += __shfl_xor(q, m);
    }
    const float mean = s * (1.f / 128.f);
    const float var  = q * (1.f / 128.f) - mean * mean;
    const float rstd = rsqrtf(var + EPS);
    rp[lane]      = (v0 - mean) * rstd * lnw[lane]      + lnb[lane];
    rp[lane + 64] = (v1 - mean) * rstd * lnw[lane + 64] + lnb[lane + 64];
}

// ---------------------------------------------------------------------------
extern "C" void kernel_launch(void* const* d_in, const int* in_sizes, int n_in,
                              void* d_out, int out_size, void* d_ws, size_t ws_size,
                              hipStream_t stream)
{
    const float* xin[5];
    for (int i = 0; i < 5; ++i) xin[i] = (const float*)d_in[i];
    const float* b_cw[2] = {(const float*)d_in[5],  (const float*)d_in[11]};
    const float* b_cb[2] = {(const float*)d_in[6],  (const float*)d_in[12]};
    const float* b_ow[2] = {(const float*)d_in[7],  (const float*)d_in[13]};
    const float* b_mw[2] = {(const float*)d_in[8],  (const float*)d_in[14]};
    const float* b_bg[2] = {(const float*)d_in[9],  (const float*)d_in[15]};
    const float* b_bb[2] = {(const float*)d_in[10], (const float*)d_in[16]};
    const float* pw[8];
    for (int i = 0; i < 8; ++i) pw[i] = (const float*)d_in[17 + i];
    const float* lnw = (const float*)d_in[25];
    const float* lnb = (const float*)d_in[26];

    float* W = (float*)d_ws;
    float* out = (float*)d_out;
    unsigned short* wB = (unsigned short*)(W + OFF_WB);
    unsigned short* wC = (unsigned short*)(W + OFF_WC);
    unsigned short* aP = (unsigned short*)(W + OFF_APROJ);
    unsigned* offa = (unsigned*)(W + OFF_OFFA);
    float* offw = W + OFF_OFFW;

    hipMemsetAsync(W + OFF_STATS, 0, 2560 * sizeof(float), stream);

    setup_conv<<<704, 256, 0, stream>>>(b_cw[0], b_cb[0], b_ow[0], b_mw[0],
        W + OFF_WCOMB, W + OFF_BCOMB, wB);
    setup_conv<<<704, 256, 0, stream>>>(b_cw[1], b_cb[1], b_ow[1], b_mw[1],
        W + OFF_WCOMB + 31104, W + OFF_BCOMB + 32, wB + 147456);
    setup_convfrag<<<144, 256, 0, stream>>>(W + OFF_WCOMB, wC);
    setup_convfrag<<<144, 256, 0, stream>>>(W + OFF_WCOMB + 31104, wC + 36864);
    setup_projA<<<760, 256, 0, stream>>>(pw[0], pw[1], pw[2], pw[3],
        pw[4], pw[5], pw[6], pw[7], aP);

    static const int Obase[5] = {0, 20, 100, 250, 460};
    static const int Ocnt[5]  = {20, 80, 150, 210, 308};
    // A-frag plane offsets (ushort) and hi-plane sizes
    static const int aOffA[5] = {0, 8192, 28672, 110592, 225280};      // c1,c2,c3a,c4a,c5a
    static const int aOffB[5] = {0, 0, 69632, 167936, 307200};         // c3b,c4b,c5b
    static const int hiSz[5]  = {4096, 10240, 20480, 28672, 40960};
    static const int yGrd[5]  = {1, 2, 3, 4, 5};                       // ceil(nOt/4)

    for (int img = 0; img < 5; ++img) {
        for (int blk = 0; blk < 2; ++blk) {
            const float* xb = (blk == 0) ? xin[img] : (W + OFF_BUFA);
            float* yb = (blk == 0) ? (W + OFF_BUFA) : (W + OFF_BUFB);
            float* st = W + OFF_STATS + (img * 2 + blk) * 256;
            conv_offm<<<1024, 512, 0, stream>>>(
                xb, wC + blk * 36864, W + OFF_BCOMB + blk * 32, offa, offw);
            deform_kernel<<<1024, 512, 0, stream>>>(
                xb, offa, offw, wB + blk * 147456, b_cb[blk], yb, st);
            norm_relu<<<2048, 256, 0, stream>>>(yb, st, b_bg[blk], b_bb[blk]);
        }
        float* outb = out + (size_t)Obase[img] * NPIX;
        proj_kernel<<<dim3(256, yGrd[img]), 256, 0, stream>>>(
            W + OFF_BUFB, aP + aOffA[img], outb, Ocnt[img], hiSz[img], 0);
        if (img >= 2)
            proj_kernel<<<dim3(256, yGrd[img]), 256, 0, stream>>>(
                xin[img], aP + aOffB[img], outb, Ocnt[img], hiSz[img], 1);
    }
    final_ln<<<24576, 256, 0, stream>>>(out, lnw, lnb);
}

// Round 4
// 692.072 us; speedup vs baseline: 1.5306x; 1.1607x over previous
//
#include <hip/hip_runtime.h>
#include <math.h>

// Problem constants
#define HH 128
#define WW 128
#define CC 128
#define KK 9
#define NPIX 16384           // H*W
#define NELEM 2097152        // NPIX*C
#define EPS 1e-5f

// Workspace layout (float offsets)
#define OFF_WCOMB 0          // [2][9][27][128] fp32      = 62208
#define OFF_BCOMB 62208      // [2][32] fp32              = 64
#define OFF_WB    62272      // fp16 B-frag deform w: 2*147456 ushort = 147456 floats
#define OFF_WC    209728     // fp16 B-frag conv w:   2*36864 ushort  = 36864 floats
#define OFF_APROJ 246592     // hi/lo bf16 A-frag proj w: 389120 ushort = 194560 floats
#define OFF_OFFA  441152     // uint2[16384*9] packed corner idx = 294912 floats
#define OFF_OFFW  736064     // float4[16384*9] weights          = 589824 floats
#define OFF_BUFA  1325888    // [16384][128]              = 2097152
#define OFF_BUFB  3423040    // [16384][128]              = 2097152
#define OFF_STATS 5520192    // [10][2][128]              = 2560
#define WS_FLOATS 5522752    // ~22.1 MB

typedef __bf16    bf16x8 __attribute__((ext_vector_type(8)));
typedef _Float16  f16x8  __attribute__((ext_vector_type(8)));
typedef float     floatx4 __attribute__((ext_vector_type(4)));

__device__ __forceinline__ unsigned short f2bf(float f) {
    unsigned u = __float_as_uint(f);
    return (unsigned short)((u + 0x7FFF + ((u >> 16) & 1)) >> 16);   // RNE
}
__device__ __forceinline__ float bf2f(unsigned short h) {
    return __uint_as_float(((unsigned)h) << 16);
}
__device__ __forceinline__ unsigned short f2h(float f) {
    _Float16 h = (_Float16)f;                                        // v_cvt_f16_f32 (RNE)
    return __builtin_bit_cast(unsigned short, h);
}

// ---------------------------------------------------------------------------
// Setup: compose [ow;mw] @ cw -> 27-ch conv weights (layout [k][o][c]),
// composed bias, and swizzle cw into fp16 MFMA B-fragment order (deform):
//   kc = s*32 + (lane>>4)*8 + j (kc = k*128+c), o = t*16 + (lane&15)
// ---------------------------------------------------------------------------
__global__ __launch_bounds__(256) void setup_conv(
    const float* __restrict__ cw, const float* __restrict__ cb,
    const float* __restrict__ ow, const float* __restrict__ mw,
    float* __restrict__ wcomb, float* __restrict__ bcomb,
    unsigned short* __restrict__ wBu)
{
    int tid = blockIdx.x * 256 + threadIdx.x;
    if (tid < 31104) {
        int c = tid & 127;
        int o = (tid >> 7) % 27;
        int k = tid / 3456;                  // k in [0,9)
        const float* sel = (o < 18) ? (ow + o * 128) : (mw + (o - 18) * 128);
        float v = 0.f;
        for (int cp = 0; cp < 128; ++cp)
            v = fmaf(sel[cp], cw[cp * 1152 + c * 9 + k], v);
        wcomb[tid] = v;                      // wcomb[k][o][c]
    } else if (tid < 31104 + 27) {
        int o = tid - 31104;
        const float* sel = (o < 18) ? (ow + o * 128) : (mw + (o - 18) * 128);
        float v = 0.f;
        for (int cp = 0; cp < 128; ++cp)
            v = fmaf(sel[cp], cb[cp], v);
        bcomb[o] = v;
    } else if (tid >= 32768 && tid < 32768 + 147456) {
        int i = tid - 32768;
        int j    = i & 7;
        int lane = (i >> 3) & 63;
        int t    = (i >> 9) & 7;
        int s    = i >> 12;                  // 0..35
        int kc   = s * 32 + ((lane >> 4) << 3) + j;
        int o    = t * 16 + (lane & 15);
        wBu[i] = f2h(cw[o * 1152 + (kc & 127) * 9 + (kc >> 7)]);
    }
}

// ---------------------------------------------------------------------------
// Swizzle composed conv weights wcomb[k][o][c] into fp16 B-frag order for the
// conv_offm MFMA (27 outputs padded to 32 -> 2 out-tiles).
// ---------------------------------------------------------------------------
__global__ __launch_bounds__(256) void setup_convfrag(
    const float* __restrict__ wcomb, unsigned short* __restrict__ wC)
{
    int i = blockIdx.x * 256 + threadIdx.x;
    if (i >= 36864) return;
    int j    = i & 7;
    int lane = (i >> 3) & 63;
    int grp  = i >> 9;                       // s*2 + t
    int t = grp & 1, s = grp >> 1;
    int kc = s * 32 + ((lane >> 4) << 3) + j;
    int o  = t * 16 + (lane & 15);
    int c = kc & 127, k = kc >> 7;
    float v = (o < 27) ? wcomb[k * 3456 + o * 128 + c] : 0.f;
    wC[i] = f2h(v);
}

// ---------------------------------------------------------------------------
// Swizzle 8 projection matrices [O][128] into hi/lo bf16 A-fragment planes.
// ---------------------------------------------------------------------------
__global__ __launch_bounds__(256) void setup_projA(
    const float* __restrict__ s0, const float* __restrict__ s1,
    const float* __restrict__ s2, const float* __restrict__ s3,
    const float* __restrict__ s4, const float* __restrict__ s5,
    const float* __restrict__ s6, const float* __restrict__ s7,
    unsigned short* __restrict__ dst)
{
    const int Os[8]   = {20, 80, 150, 150, 210, 210, 308, 308};
    const int nOt[8]  = {2, 5, 10, 10, 14, 14, 20, 20};
    const int tOff[8] = {0, 4096, 14336, 34816, 55296, 83968, 112640, 153600};
    const int dOff[8] = {0, 8192, 28672, 69632, 110592, 167936, 225280, 307200};
    int tid = blockIdx.x * 256 + threadIdx.x;
    if (tid >= 194560) return;
    int m = 0;
    #pragma unroll
    for (int q = 1; q < 8; ++q) if (tid >= tOff[q]) m = q;
    const float* src;
    switch (m) {
        case 0: src = s0; break; case 1: src = s1; break;
        case 2: src = s2; break; case 3: src = s3; break;
        case 4: src = s4; break; case 5: src = s5; break;
        case 6: src = s6; break; default: src = s7; break;
    }
    int i = tid - tOff[m];
    int j    = i & 7;
    int lane = (i >> 3) & 63;
    int s    = (i >> 9) & 3;
    int ot   = i >> 11;
    int o = ot * 16 + (lane & 15);
    int c = s * 32 + ((lane >> 4) << 3) + j;
    float v = (o < Os[m]) ? src[o * 128 + c] : 0.f;
    unsigned short h = f2bf(v);
    unsigned short l = f2bf(v - bf2f(h));
    const int hiSize = nOt[m] * 2048;
    dst[dOff[m] + i] = h;
    dst[dOff[m] + hiSize + i] = l;
}

// ---------------------------------------------------------------------------
// conv_offm, 512 threads (8 waves), 16 px/block. NORM: fold previous block's
// BN+ReLU into the gather (x is raw conv output; stats st + bg/bb give
// per-channel scale/shift; v' = max(fma(v,sc,sh),0) == old norm_relu).
// MFMA: wave = (t = wid&1, kq = wid>>1), 9 K-steps with B prefetch; 4-way
// K-reduction through recycled LDS. Epilogue emits packed bilinear gather
// descriptors (corner indices + mask-folded weights).
// ---------------------------------------------------------------------------
template <bool NORM>
__global__ __launch_bounds__(512, 8) void conv_offm(
    const float* __restrict__ x, const unsigned short* __restrict__ wC,
    const float* __restrict__ bcomb, const float* __restrict__ st,
    const float* __restrict__ bg, const float* __restrict__ bb,
    unsigned* __restrict__ offa, float* __restrict__ offw)
{
    __shared__ unsigned short smp[16 * 1160];   // 37120 B
    float* red  = (float*)smp;                  // recycled: [3][2][16][16] = 1536 f
    float* vals = red + 1536;                   // recycled: [16][33]       = 528 f
    float* maskL = red;                         // recycled again: [16][9]

    const int lane = threadIdx.x & 63;
    const int wid  = threadIdx.x >> 6;          // 0..7
    const int gp0  = blockIdx.x * 16;
    const int half = lane >> 5;
    const int cl   = lane & 31;                 // channel-quad index
    const float4* x4 = (const float4*)x;

    float sc4[4], sh4[4];
    if constexpr (NORM) {
        #pragma unroll
        for (int j = 0; j < 4; ++j) {
            const int c = cl * 4 + j;
            const float mean = st[c] * (1.f / 16384.f);
            const float var  = st[128 + c] * (1.f / 16384.f) - mean * mean;
            const float rstd = rsqrtf(var + EPS);
            sc4[j] = bg[c] * rstd;
            sh4[j] = bb[c] - mean * sc4[j];
        }
    }

    // ---- gather: wave wid handles pixels 2*wid + half ----
    {
        const int pl = wid * 2 + half;
        const int gp = gp0 + pl;
        const int h0 = gp >> 7, w0 = gp & 127;
        unsigned* dstq = (unsigned*)smp + pl * 580 + cl * 2;
        #pragma unroll
        for (int k = 0; k < 9; ++k) {
            const int ny = h0 + k / 3 - 1;
            const int nx = w0 + k % 3 - 1;
            const int cy = min(max(ny, 0), 127);
            const int cx = min(max(nx, 0), 127);
            float4 v = x4[(((cy << 7) + cx) << 5) + cl];
            if constexpr (NORM) {
                v.x = fmaxf(fmaf(v.x, sc4[0], sh4[0]), 0.f);
                v.y = fmaxf(fmaf(v.y, sc4[1], sh4[1]), 0.f);
                v.z = fmaxf(fmaf(v.z, sc4[2], sh4[2]), 0.f);
                v.w = fmaxf(fmaf(v.w, sc4[3], sh4[3]), 0.f);
            }
            const bool ok = ((unsigned)ny < 128u) & ((unsigned)nx < 128u);
            unsigned d0 = (unsigned)f2h(v.x) | ((unsigned)f2h(v.y) << 16);
            unsigned d1 = (unsigned)f2h(v.z) | ((unsigned)f2h(v.w) << 16);
            d0 = ok ? d0 : 0u;
            d1 = ok ? d1 : 0u;
            *(uint2*)(dstq + k * 64) = make_uint2(d0, d1);
        }
    }
    __syncthreads();

    // ---- MFMA: wave = (t = wid&1, kq = wid>>1), 9 K-steps each ----
    const int t    = wid & 1;
    const int kq   = wid >> 1;
    const int mrow = lane & 15;
    const int quad = lane >> 4;
    floatx4 acc = {0.f, 0.f, 0.f, 0.f};
    const unsigned short* arow = smp + mrow * 1160 + quad * 8;
    const unsigned short* bbase = wC + t * 512 + (lane << 3);
    f16x8 b = *(const f16x8*)(bbase + (kq * 9) * 1024);
    #pragma unroll
    for (int j = 0; j < 9; ++j) {
        const int s = kq * 9 + j;
        f16x8 nb;
        if (j < 8) nb = *(const f16x8*)(bbase + (s + 1) * 1024);
        const f16x8 a = *(const f16x8*)(arow + s * 32);
        acc = __builtin_amdgcn_mfma_f32_16x16x32_f16(a, b, acc, 0, 0, 0);
        if (j < 8) b = nb;
    }
    __syncthreads();   // all smp reads done; safe to recycle as red/vals

    // D: row (pixel) = quad*4+r, col (channel) = lane&15
    if (kq > 0) {
        #pragma unroll
        for (int r = 0; r < 4; ++r)
            red[(((kq - 1) * 2 + t) << 8) + (quad * 4 + r) * 16 + mrow] = acc[r];
    }
    __syncthreads();
    if (kq == 0) {
        #pragma unroll
        for (int r = 0; r < 4; ++r) {
            const int rc = (quad * 4 + r) * 16 + mrow;
            const float sv = acc[r] + red[(t << 8) + rc]
                           + red[((2 + t) << 8) + rc] + red[((4 + t) << 8) + rc];
            vals[(quad * 4 + r) * 33 + t * 16 + mrow] = sv;
        }
    }
    __syncthreads();

    // ---- epilogue A: lanes < 16 compute softmax masks into maskL ----
    if (threadIdx.x < 16) {
        const int p = threadIdx.x;
        const float* vp = vals + p * 33;
        float e[9], se = 0.f, mx = -1e30f;
        #pragma unroll
        for (int k = 0; k < 9; ++k) {
            e[k] = vp[18 + k] + bcomb[18 + k];
            mx = fmaxf(mx, e[k]);
        }
        #pragma unroll
        for (int k = 0; k < 9; ++k) { e[k] = expf(e[k] - mx); se += e[k]; }
        const float inv = 1.f / se;
        #pragma unroll
        for (int k = 0; k < 9; ++k) maskL[p * 9 + k] = e[k] * inv;
    }
    __syncthreads();

    // ---- epilogue B: 144 threads emit packed gather descriptors ----
    if (threadIdx.x < 144) {
        const int p = threadIdx.x / 9;
        const int k = threadIdx.x - p * 9;
        const int gp = gp0 + p;
        const int hh = gp >> 7, ww = gp & 127;
        const float* vp = vals + p * 33;
        const float py = (float)(hh - 1 + k / 3) + vp[2 * k]     + bcomb[2 * k];
        const float px = (float)(ww - 1 + k % 3) + vp[2 * k + 1] + bcomb[2 * k + 1];
        const float mk = maskL[p * 9 + k];
        const float y0f = floorf(py), x0f = floorf(px);
        const int iy0 = (int)y0f, ix0 = (int)x0f;
        const float wy1 = py - y0f, wy0 = 1.f - wy1;
        const float wx1 = px - x0f, wx0 = 1.f - wx1;
        const int cy0 = min(max(iy0, 0), 127);
        const int cy1 = min(max(iy0 + 1, 0), 127);
        const int cx0 = min(max(ix0, 0), 127);
        const int cx1 = min(max(ix0 + 1, 0), 127);
        const float vy0 = ((unsigned)iy0       < 128u) ? 1.f : 0.f;
        const float vy1 = ((unsigned)(iy0 + 1) < 128u) ? 1.f : 0.f;
        const float vx0 = ((unsigned)ix0       < 128u) ? 1.f : 0.f;
        const float vx1 = ((unsigned)(ix0 + 1) < 128u) ? 1.f : 0.f;
        const float w00 = wy0 * wx0 * vy0 * vx0 * mk;
        const float w01 = wy0 * wx1 * vy0 * vx1 * mk;
        const float w10 = wy1 * wx0 * vy1 * vx0 * mk;
        const float w11 = wy1 * wx1 * vy1 * vx1 * mk;
        const unsigned i00 = (unsigned)((cy0 << 7) | cx0);
        const unsigned i01 = (unsigned)((cy0 << 7) | cx1);
        const unsigned i10 = (unsigned)((cy1 << 7) | cx0);
        const unsigned i11 = (unsigned)((cy1 << 7) | cx1);
        ((uint2*)offa)[(size_t)gp * 9 + k] =
            make_uint2(i00 | (i01 << 16), i10 | (i11 << 16));
        ((float4*)offw)[(size_t)gp * 9 + k] = make_float4(w00, w01, w10, w11);
    }
}

// ---------------------------------------------------------------------------
// deform, 512 threads (8 waves), 32 px/block (512 blocks). Gather reads
// precomputed descriptors; NORM folds BN+ReLU per corner (must precede the
// bilinear weighting since ReLU is nonlinear). MFMA: wave wid owns N-tile
// wid over M=32 px as 2 M-subtiles -> each B fragment feeds 2 MFMAs (B
// L2-latency chain per pixel halves vs 16-px blocks); 2-deep B prefetch.
// LDS 74.2 KB -> 2 blocks/CU, 4 waves/SIMD, VGPR budget 128 (gather MLP was
// VGPR-starved at 32). Epilogue: store + fused per-channel sum/sumsq stats.
// ---------------------------------------------------------------------------
template <bool NORM>
__global__ __launch_bounds__(512, 4) void deform_kernel(
    const float* __restrict__ x, const unsigned* __restrict__ offa,
    const float* __restrict__ offw, const unsigned short* __restrict__ wBu,
    const float* __restrict__ cb, const float* __restrict__ stp,
    const float* __restrict__ bg, const float* __restrict__ bb,
    float* __restrict__ y, float* __restrict__ st)
{
    __shared__ unsigned short smp[32 * 1160];   // 74240 B

    const int lane = threadIdx.x & 63;
    const int wid  = threadIdx.x >> 6;          // 0..7
    const int gp0  = blockIdx.x * 32;
    const int half = lane >> 5;
    const int cl   = lane & 31;
    const float4* x4 = (const float4*)x;

    float sc4[4], sh4[4];
    if constexpr (NORM) {
        #pragma unroll
        for (int j = 0; j < 4; ++j) {
            const int c = cl * 4 + j;
            const float mean = stp[c] * (1.f / 16384.f);
            const float var  = stp[128 + c] * (1.f / 16384.f) - mean * mean;
            const float rstd = rsqrtf(var + EPS);
            sc4[j] = bg[c] * rstd;
            sh4[j] = bb[c] - mean * sc4[j];
        }
    }

    // ---- phase 1: wave wid gathers pixels wid*4 + pass*2 + half ----
    for (int pass = 0; pass < 2; ++pass) {
        const int pl = wid * 4 + pass * 2 + half;
        const size_t tb = (size_t)(gp0 + pl) * 9;
        const uint2*  ap = (const uint2*)offa + tb;
        const float4* wp = (const float4*)offw + tb;
        unsigned* dstq = (unsigned*)smp + pl * 580 + cl * 2;
        #pragma unroll
        for (int k = 0; k < 9; ++k) {
            const uint2  a = ap[k];
            const float4 w = wp[k];
            const int i00 = (int)(a.x & 0xFFFFu) << 5;
            const int i01 = (int)(a.x >> 16) << 5;
            const int i10 = (int)(a.y & 0xFFFFu) << 5;
            const int i11 = (int)(a.y >> 16) << 5;
            float4 g00 = x4[i00 + cl];
            float4 g01 = x4[i01 + cl];
            float4 g10 = x4[i10 + cl];
            float4 g11 = x4[i11 + cl];
            if constexpr (NORM) {
                g00.x = fmaxf(fmaf(g00.x, sc4[0], sh4[0]), 0.f);
                g00.y = fmaxf(fmaf(g00.y, sc4[1], sh4[1]), 0.f);
                g00.z = fmaxf(fmaf(g00.z, sc4[2], sh4[2]), 0.f);
                g00.w = fmaxf(fmaf(g00.w, sc4[3], sh4[3]), 0.f);
                g01.x = fmaxf(fmaf(g01.x, sc4[0], sh4[0]), 0.f);
                g01.y = fmaxf(fmaf(g01.y, sc4[1], sh4[1]), 0.f);
                g01.z = fmaxf(fmaf(g01.z, sc4[2], sh4[2]), 0.f);
                g01.w = fmaxf(fmaf(g01.w, sc4[3], sh4[3]), 0.f);
                g10.x = fmaxf(fmaf(g10.x, sc4[0], sh4[0]), 0.f);
                g10.y = fmaxf(fmaf(g10.y, sc4[1], sh4[1]), 0.f);
                g10.z = fmaxf(fmaf(g10.z, sc4[2], sh4[2]), 0.f);
                g10.w = fmaxf(fmaf(g10.w, sc4[3], sh4[3]), 0.f);
                g11.x = fmaxf(fmaf(g11.x, sc4[0], sh4[0]), 0.f);
                g11.y = fmaxf(fmaf(g11.y, sc4[1], sh4[1]), 0.f);
                g11.z = fmaxf(fmaf(g11.z, sc4[2], sh4[2]), 0.f);
                g11.w = fmaxf(fmaf(g11.w, sc4[3], sh4[3]), 0.f);
            }
            const float s0 = fmaf(w.x, g00.x, fmaf(w.y, g01.x, fmaf(w.z, g10.x, w.w * g11.x)));
            const float s1 = fmaf(w.x, g00.y, fmaf(w.y, g01.y, fmaf(w.z, g10.y, w.w * g11.y)));
            const float s2 = fmaf(w.x, g00.z, fmaf(w.y, g01.z, fmaf(w.z, g10.z, w.w * g11.z)));
            const float s3 = fmaf(w.x, g00.w, fmaf(w.y, g01.w, fmaf(w.z, g10.w, w.w * g11.w)));
            const unsigned d0 = (unsigned)f2h(s0) | ((unsigned)f2h(s1) << 16);
            const unsigned d1 = (unsigned)f2h(s2) | ((unsigned)f2h(s3) << 16);
            *(uint2*)(dstq + k * 64) = make_uint2(d0, d1);
        }
    }
    __syncthreads();

    // ---- phase 2: wave wid owns N-tile wid, M = 2 subtiles, K = 36 ----
    const int mrow = lane & 15;
    const int quad = lane >> 4;
    const unsigned short* arow0 = smp + mrow * 1160 + quad * 8;
    const unsigned short* arow1 = arow0 + 16 * 1160;
    const unsigned short* bbase = wBu + wid * 512 + (lane << 3);
    floatx4 acc0 = {0.f, 0.f, 0.f, 0.f};
    floatx4 acc1 = {0.f, 0.f, 0.f, 0.f};
    f16x8 b0 = *(const f16x8*)(bbase);
    f16x8 b1 = *(const f16x8*)(bbase + 4096);
    #pragma unroll
    for (int s = 0; s < 36; ++s) {
        f16x8 b2;
        if (s < 34) b2 = *(const f16x8*)(bbase + (size_t)(s + 2) * 4096);
        const f16x8 a0 = *(const f16x8*)(arow0 + s * 32);
        const f16x8 a1 = *(const f16x8*)(arow1 + s * 32);
        acc0 = __builtin_amdgcn_mfma_f32_16x16x32_f16(a0, b0, acc0, 0, 0, 0);
        acc1 = __builtin_amdgcn_mfma_f32_16x16x32_f16(a1, b0, acc1, 0, 0, 0);
        b0 = b1;
        if (s < 34) b1 = b2;
    }

    // ---- epilogue: store + per-channel stats (channel n = wid*16+mrow) ----
    const int n = wid * 16 + mrow;
    const float bias = cb[n];
    float ssum = 0.f, qsum = 0.f;
    #pragma unroll
    for (int r = 0; r < 4; ++r) {
        const float v0 = acc0[r] + bias;
        const float v1 = acc1[r] + bias;
        y[(size_t)(gp0 + quad * 4 + r) * 128 + n] = v0;
        y[(size_t)(gp0 + 16 + quad * 4 + r) * 128 + n] = v1;
        ssum += v0 + v1;
        qsum = fmaf(v0, v0, qsum);
        qsum = fmaf(v1, v1, qsum);
    }
    ssum += __shfl_xor(ssum, 16); qsum += __shfl_xor(qsum, 16);
    ssum += __shfl_xor(ssum, 32); qsum += __shfl_xor(qsum, 32);
    if (quad == 0) {
        atomicAdd(&st[n], ssum);
        atomicAdd(&st[128 + n], qsum);
    }
}

// ---------------------------------------------------------------------------
// 1x1 projection as hi/lo-split bf16 MFMA GEMM (fp32-accurate).
// blockIdx.y splits the out-tile dim. Optional fused BN+ReLU on the input
// (stn != nullptr): replaces the old norm_relu pass for BUFB.
// ---------------------------------------------------------------------------
__global__ __launch_bounds__(256) void proj_kernel(
    const float* __restrict__ xin, const unsigned short* __restrict__ aP,
    const float* __restrict__ stn, const float* __restrict__ bgn,
    const float* __restrict__ bbn,
    float* __restrict__ out, int O, int hiSize, int accum)
{
    __shared__ unsigned short sh[64 * 136];
    __shared__ unsigned short sl[64 * 136];
    const int gp0 = blockIdx.x * 64;

    // stage 64 px x 128 c, split into hi/lo bf16 (dword-packed writes)
    for (int i = threadIdx.x; i < 4096; i += 256) {
        const int p = i >> 6, c2 = (i & 63) * 2;
        float2 v = *(const float2*)(xin + (gp0 + p) * 128 + c2);
        if (stn) {
            #pragma unroll
            for (int j = 0; j < 2; ++j) {
                const int c = c2 + j;
                const float mean = stn[c] * (1.f / 16384.f);
                const float var  = stn[128 + c] * (1.f / 16384.f) - mean * mean;
                const float rstd = rsqrtf(var + EPS);
                const float scn = bgn[c] * rstd;
                const float shn = bbn[c] - mean * scn;
                float vv = j ? v.y : v.x;
                vv = fmaxf(fmaf(vv, scn, shn), 0.f);
                if (j) v.y = vv; else v.x = vv;
            }
        }
        const unsigned short h0 = f2bf(v.x), h1 = f2bf(v.y);
        const unsigned short l0 = f2bf(v.x - bf2f(h0)), l1 = f2bf(v.y - bf2f(h1));
        ((unsigned*)sh)[p * 68 + (c2 >> 1)] = (unsigned)h0 | ((unsigned)h1 << 16);
        ((unsigned*)sl)[p * 68 + (c2 >> 1)] = (unsigned)l0 | ((unsigned)l1 << 16);
    }
    __syncthreads();

    const int lane = threadIdx.x & 63;
    const int wid  = threadIdx.x >> 6;
    const int quad = lane >> 4;
    const int nrow = lane & 15;
    const int nOt  = (O + 15) >> 4;
    const int ot   = blockIdx.y * 4 + wid;

    if (ot < nOt) {
        bf16x8 Ah[4], Al[4];
        #pragma unroll
        for (int s = 0; s < 4; ++s) {
            const int idx = ((ot * 4 + s) * 64 + lane) * 8;
            Ah[s] = *(const bf16x8*)(aP + idx);
            Al[s] = *(const bf16x8*)(aP + hiSize + idx);
        }
        #pragma unroll
        for (int pt = 0; pt < 4; ++pt) {
            floatx4 acc = {0.f, 0.f, 0.f, 0.f};
            const int roff = (pt * 16 + nrow) * 136 + quad * 8;
            #pragma unroll
            for (int s = 0; s < 4; ++s) {
                const bf16x8 Bh = *(const bf16x8*)(sh + roff + s * 32);
                const bf16x8 Bl = *(const bf16x8*)(sl + roff + s * 32);
                acc = __builtin_amdgcn_mfma_f32_16x16x32_bf16(Ah[s], Bh, acc, 0, 0, 0);
                acc = __builtin_amdgcn_mfma_f32_16x16x32_bf16(Al[s], Bh, acc, 0, 0, 0);
                acc = __builtin_amdgcn_mfma_f32_16x16x32_bf16(Ah[s], Bl, acc, 0, 0, 0);
            }
            #pragma unroll
            for (int r = 0; r < 4; ++r) {
                const int o = ot * 16 + quad * 4 + r;
                if (o < O) {
                    float* dst = out + (size_t)o * NPIX + gp0 + pt * 16 + nrow;
                    *dst = accum ? (*dst + acc[r]) : acc[r];
                }
            }
        }
    }
}

// ---------------------------------------------------------------------------
// Final layernorm over the W axis: one wave per (c,h) row of 128.
// ---------------------------------------------------------------------------
__global__ __launch_bounds__(256) void final_ln(
    float* __restrict__ out, const float* __restrict__ lnw,
    const float* __restrict__ lnb)
{
    const int lane = threadIdx.x & 63;
    const int wid  = threadIdx.x >> 6;
    const int row  = blockIdx.x * 4 + wid;          // 98304 rows
    float* rp = out + row * 128;
    const float v0 = rp[lane], v1 = rp[lane + 64];
    float s = v0 + v1;
    float q = v0 * v0 + v1 * v1;
    #pragma unroll
    for (int m = 32; m; m >>= 1) {
        s += __shfl_xor(s, m);
        q += __shfl_xor(q, m);
    }
    const float mean = s * (1.f / 128.f);
    const float var  = q * (1.f / 128.f) - mean * mean;
    const float rstd = rsqrtf(var + EPS);
    rp[lane]      = (v0 - mean) * rstd * lnw[lane]      + lnb[lane];
    rp[lane + 64] = (v1 - mean) * rstd * lnw[lane + 64] + lnb[lane + 64];
}

// ---------------------------------------------------------------------------
extern "C" void kernel_launch(void* const* d_in, const int* in_sizes, int n_in,
                              void* d_out, int out_size, void* d_ws, size_t ws_size,
                              hipStream_t stream)
{
    const float* xin[5];
    for (int i = 0; i < 5; ++i) xin[i] = (const float*)d_in[i];
    const float* b_cw[2] = {(const float*)d_in[5],  (const float*)d_in[11]};
    const float* b_cb[2] = {(const float*)d_in[6],  (const float*)d_in[12]};
    const float* b_ow[2] = {(const float*)d_in[7],  (const float*)d_in[13]};
    const float* b_mw[2] = {(const float*)d_in[8],  (const float*)d_in[14]};
    const float* b_bg[2] = {(const float*)d_in[9],  (const float*)d_in[15]};
    const float* b_bb[2] = {(const float*)d_in[10], (const float*)d_in[16]};
    const float* pw[8];
    for (int i = 0; i < 8; ++i) pw[i] = (const float*)d_in[17 + i];
    const float* lnw = (const float*)d_in[25];
    const float* lnb = (const float*)d_in[26];

    float* W = (float*)d_ws;
    float* out = (float*)d_out;
    unsigned short* wB = (unsigned short*)(W + OFF_WB);
    unsigned short* wC = (unsigned short*)(W + OFF_WC);
    unsigned short* aP = (unsigned short*)(W + OFF_APROJ);
    unsigned* offa = (unsigned*)(W + OFF_OFFA);
    float* offw = W + OFF_OFFW;

    hipMemsetAsync(W + OFF_STATS, 0, 2560 * sizeof(float), stream);

    setup_conv<<<704, 256, 0, stream>>>(b_cw[0], b_cb[0], b_ow[0], b_mw[0],
        W + OFF_WCOMB, W + OFF_BCOMB, wB);
    setup_conv<<<704, 256, 0, stream>>>(b_cw[1], b_cb[1], b_ow[1], b_mw[1],
        W + OFF_WCOMB + 31104, W + OFF_BCOMB + 32, wB + 147456);
    setup_convfrag<<<144, 256, 0, stream>>>(W + OFF_WCOMB, wC);
    setup_convfrag<<<144, 256, 0, stream>>>(W + OFF_WCOMB + 31104, wC + 36864);
    setup_projA<<<760, 256, 0, stream>>>(pw[0], pw[1], pw[2], pw[3],
        pw[4], pw[5], pw[6], pw[7], aP);

    static const int Obase[5] = {0, 20, 100, 250, 460};
    static const int Ocnt[5]  = {20, 80, 150, 210, 308};
    // A-frag plane offsets (ushort) and hi-plane sizes
    static const int aOffA[5] = {0, 8192, 28672, 110592, 225280};      // c1,c2,c3a,c4a,c5a
    static const int aOffB[5] = {0, 0, 69632, 167936, 307200};         // c3b,c4b,c5b
    static const int hiSz[5]  = {4096, 10240, 20480, 28672, 40960};
    static const int yGrd[5]  = {1, 2, 3, 4, 5};                       // ceil(nOt/4)

    for (int img = 0; img < 5; ++img) {
        for (int blk = 0; blk < 2; ++blk) {
            const float* xb = (blk == 0) ? xin[img] : (W + OFF_BUFA);
            float* yb = (blk == 0) ? (W + OFF_BUFA) : (W + OFF_BUFB);
            float* st = W + OFF_STATS + (img * 2 + blk) * 256;
            const float* stp = W + OFF_STATS + (img * 2) * 256;  // stats of blk0
            if (blk == 0) {
                conv_offm<false><<<1024, 512, 0, stream>>>(
                    xb, wC, W + OFF_BCOMB, nullptr, nullptr, nullptr, offa, offw);
                deform_kernel<false><<<512, 512, 0, stream>>>(
                    xb, offa, offw, wB, b_cb[0], nullptr, nullptr, nullptr, yb, st);
            } else {
                conv_offm<true><<<1024, 512, 0, stream>>>(
                    xb, wC + 36864, W + OFF_BCOMB + 32, stp, b_bg[0], b_bb[0],
                    offa, offw);
                deform_kernel<true><<<512, 512, 0, stream>>>(
                    xb, offa, offw, wB + 147456, b_cb[1], stp, b_bg[0], b_bb[0],
                    yb, st);
            }
        }
        const float* st1 = W + OFF_STATS + (img * 2 + 1) * 256;
        float* outb = out + (size_t)Obase[img] * NPIX;
        proj_kernel<<<dim3(256, yGrd[img]), 256, 0, stream>>>(
            W + OFF_BUFB, aP + aOffA[img], st1, b_bg[1], b_bb[1],
            outb, Ocnt[img], hiSz[img], 0);
        if (img >= 2)
            proj_kernel<<<dim3(256, yGrd[img]), 256, 0, stream>>>(
                xin[img], aP + aOffB[img], nullptr, nullptr, nullptr,
                outb, Ocnt[img], hiSz[img], 1);
    }
    final_ln<<<24576, 256, 0, stream>>>(out, lnw, lnb);
}